// Round 2
// baseline (712.292 us; speedup 1.0000x reference)
//
#include <hip/hip_runtime.h>
#include <hip/hip_bf16.h>

#define V_  5
#define B_  2
#define C_  32
#define H_  128
#define W_  160
#define D_  32
#define G_  8
#define HW_  (H_*W_)
#define DHW_ (D_*HW_)

#define LOG2E_ 1.4426950408889634f
#define LN2_   0.6931471805599453f
#define LN8_   2.0794415416798357f

// ws layout (floats): [0..95] proj | [128..1151] mlp table | [2048 ...] featT (26.2MB) / hid (41.9MB, overwrites featT)

// ---------------- projection + MLP table setup ----------------

__device__ inline void combine_mat(const float* m, float out[4][4]) {
    const float* ext = m;
    const float* K   = m + 16;
    for (int r = 0; r < 4; ++r)
        for (int c = 0; c < 4; ++c)
            out[r][c] = ext[r*4 + c];
    for (int r = 0; r < 3; ++r)
        for (int c = 0; c < 4; ++c) {
            float s = 0.f;
            for (int k = 0; k < 3; ++k) s += K[r*4 + k] * ext[k*4 + c];
            out[r][c] = s;
        }
}

__device__ inline void invert4(const float Ain[4][4], float Inv[4][4]) {
    float A[4][4];
    for (int r = 0; r < 4; ++r)
        for (int c = 0; c < 4; ++c) {
            A[r][c]   = Ain[r][c];
            Inv[r][c] = (r == c) ? 1.f : 0.f;
        }
    for (int k = 0; k < 4; ++k) {
        int p = k; float best = fabsf(A[k][k]);
        for (int r = k + 1; r < 4; ++r) {
            float v = fabsf(A[r][k]);
            if (v > best) { best = v; p = r; }
        }
        if (p != k) {
            for (int j = 0; j < 4; ++j) {
                float t = A[k][j]; A[k][j] = A[p][j]; A[p][j] = t;
                t = Inv[k][j]; Inv[k][j] = Inv[p][j]; Inv[p][j] = t;
            }
        }
        float dinv = 1.f / A[k][k];
        for (int j = 0; j < 4; ++j) { A[k][j] *= dinv; Inv[k][j] *= dinv; }
        for (int r = 0; r < 4; ++r) {
            if (r == k) continue;
            float f = A[r][k];
            for (int j = 0; j < 4; ++j) {
                A[r][j]  -= f * A[k][j];
                Inv[r][j] -= f * Inv[k][j];
            }
        }
    }
}

__global__ __launch_bounds__(1024) void k_proj(
    const float* __restrict__ pm,
    const float* __restrict__ pw_w1, const float* __restrict__ pw_b1,
    const float* __restrict__ pw_w2, const float* __restrict__ pw_b2,
    const float* __restrict__ pw_w3, const float* __restrict__ pw_b3,
    float* __restrict__ proj_ws, float* __restrict__ tabw)
{
    int tid = threadIdx.x;
    if (tid < B_) {
        int b = tid;
        float C0[4][4], C0inv[4][4];
        combine_mat(pm + (b * V_ + 0) * 32, C0);
        invert4(C0, C0inv);
        for (int v = 1; v < V_; ++v) {
            float Cv[4][4];
            combine_mat(pm + (b * V_ + v) * 32, Cv);
            float* o = proj_ws + (b * 4 + (v - 1)) * 12;
            for (int r = 0; r < 3; ++r)
                for (int c = 0; c < 4; ++c) {
                    float s = 0.f;
                    for (int k = 0; k < 4; ++k) s += Cv[r][k] * C0inv[k][c];
                    o[r*4 + c] = s;
                }
        }
    }
    // MLP sigmoid table over ent in [0, ln 8]
    float ent = (float)tid * (LN8_ / 1023.0f);
    float h2[8];
    #pragma unroll
    for (int j = 0; j < 8; ++j) h2[j] = pw_b2[j];
    for (int k = 0; k < 16; ++k) {
        float h1 = fmaxf(ent * pw_w1[k] + pw_b1[k], 0.f);
        #pragma unroll
        for (int j = 0; j < 8; ++j) h2[j] += pw_w2[j*16 + k] * h1;
    }
    float o3 = pw_b3[0];
    #pragma unroll
    for (int j = 0; j < 8; ++j) o3 += pw_w3[j] * fmaxf(h2[j], 0.f);
    tabw[tid] = 1.f / (1.f + expf(-o3));
}

// ---------------- feature transpose: [V][B][C][H][W] -> [VB][HW][C] ----------------
__global__ __launch_bounds__(1024) void k_transpose(
    const float* __restrict__ in, float* __restrict__ out)
{
    __shared__ float s[32][33];
    const int tx = threadIdx.x, ty = threadIdx.y;
    const int hw0 = blockIdx.x * 32;
    const int vb  = blockIdx.y;
    s[ty][tx] = in[(vb * 32 + ty) * HW_ + hw0 + tx];
    __syncthreads();
    out[(vb * HW_ + hw0 + ty) * 32 + tx] = s[tx][ty];
}

// ---------------- main fused kernel ----------------
// grid (W/32, H, B), block (32, 32): thread = (w, d)
__global__ __launch_bounds__(1024, 4) void k_main(
    const float* __restrict__ featT,    // [VB][HW][32]
    const float* __restrict__ depthv,   // [B][D][H][W]
    const float* __restrict__ proj_ws,
    const float* __restrict__ tabw,     // 1024 sigmoid table
    float* __restrict__ out_vw,         // [B][4][H][W]
    float* __restrict__ out_sim)        // [B][G][D][H][W]
{
    const int tx = threadIdx.x;
    const int ty = threadIdx.y;          // d
    const int w0 = blockIdx.x * 32;
    const int h  = blockIdx.y;
    const int b  = blockIdx.z;
    const int w  = w0 + tx;
    const int tid = ty * 32 + tx;
    const int p  = h * W_ + w;

    __shared__ float2 tab_s[1024];
    __shared__ float red[32][32];
    __shared__ float vw_s[32];
    __shared__ float proj_s[48];

    tab_s[tid] = make_float2(tabw[tid], tabw[tid < 1023 ? tid + 1 : 1023]);
    if (tid < 48) proj_s[tid] = proj_ws[b * 48 + tid];
    __syncthreads();

    // ref fragment (view 0) into registers: 8 float4 = 32 ch
    const float4* rp = (const float4*)(featT + ((size_t)(0 * B_ + b) * HW_ + p) * 32);
    float4 refv[8];
    #pragma unroll
    for (int cc = 0; cc < 8; ++cc) refv[cc] = rp[cc];

    const int d = ty;
    const float depth = depthv[(b * D_ + d) * HW_ + p];
    const float xf = (float)w, yf = (float)h;

    float simsum[G_];
    #pragma unroll
    for (int g = 0; g < G_; ++g) simsum[g] = 0.f;
    float wsum = 0.f;

    for (int v = 1; v < V_; ++v) {
        const float* P = &proj_s[(v - 1) * 12];
        float px = (P[0]*xf + P[1]*yf + P[2])  * depth + P[3];
        float py = (P[4]*xf + P[5]*yf + P[6])  * depth + P[7];
        float pz = (P[8]*xf + P[9]*yf + P[10]) * depth + P[11];
        float rz = __builtin_amdgcn_rcpf(pz);
        float xs = px * rz;
        float ys = py * rz;

        float x0 = floorf(xs), y0 = floorf(ys);
        float wx1 = xs - x0,  wy1 = ys - y0;
        float wx0 = 1.f - wx1, wy0 = 1.f - wy1;

        bool vx0 = (x0 >= 0.f)     && (x0 <= (float)(W_-1));
        bool vx1 = (x0+1.f >= 0.f) && (x0+1.f <= (float)(W_-1));
        bool vy0 = (y0 >= 0.f)     && (y0 <= (float)(H_-1));
        bool vy1 = (y0+1.f >= 0.f) && (y0+1.f <= (float)(H_-1));

        int xc0 = (int)fminf(fmaxf(x0,     0.f), (float)(W_-1));
        int xc1 = (int)fminf(fmaxf(x0+1.f, 0.f), (float)(W_-1));
        int yc0 = (int)fminf(fmaxf(y0,     0.f), (float)(H_-1));
        int yc1 = (int)fminf(fmaxf(y0+1.f, 0.f), (float)(H_-1));

        float w00 = (vx0 && vy0) ? (wx0 * wy0) : 0.f;
        float w01 = (vx1 && vy0) ? (wx1 * wy0) : 0.f;
        float w10 = (vx0 && vy1) ? (wx0 * wy1) : 0.f;
        float w11 = (vx1 && vy1) ? (wx1 * wy1) : 0.f;

        const float* vbp = featT + (size_t)(v * B_ + b) * HW_ * 32;
        const float4* p00 = (const float4*)(vbp + (yc0 * W_ + xc0) * 32);
        const float4* p01 = (const float4*)(vbp + (yc0 * W_ + xc1) * 32);
        const float4* p10 = (const float4*)(vbp + (yc1 * W_ + xc0) * 32);
        const float4* p11 = (const float4*)(vbp + (yc1 * W_ + xc1) * 32);

        float sim[G_];
        #pragma unroll
        for (int cc = 0; cc < 8; ++cc) {
            float4 a = p00[cc], bq = p01[cc], cq = p10[cc], dq = p11[cc];
            float vx = fmaf(dq.x, w11, fmaf(cq.x, w10, fmaf(bq.x, w01, a.x * w00)));
            float vy = fmaf(dq.y, w11, fmaf(cq.y, w10, fmaf(bq.y, w01, a.y * w00)));
            float vz = fmaf(dq.z, w11, fmaf(cq.z, w10, fmaf(bq.z, w01, a.z * w00)));
            float vw4= fmaf(dq.w, w11, fmaf(cq.w, w10, fmaf(bq.w, w01, a.w * w00)));
            float4 rv = refv[cc];
            float dot = fmaf(vx, rv.x, fmaf(vy, rv.y, fmaf(vz, rv.z, vw4 * rv.w)));
            sim[cc] = dot * 0.25f;
        }

        // entropy of softmax(sim): ent = m + ln(es) - (sum e*sim)/es
        float m = sim[0];
        #pragma unroll
        for (int g = 1; g < G_; ++g) m = fmaxf(m, sim[g]);
        float es = 0.f, edot = 0.f;
        #pragma unroll
        for (int g = 0; g < G_; ++g) {
            float e = exp2f((sim[g] - m) * LOG2E_);
            es += e;
            edot = fmaf(e, sim[g], edot);
        }
        float inv_es = __builtin_amdgcn_rcpf(es);
        float ent = m + log2f(es) * LN2_ - edot * inv_es;

        // sigmoid(MLP(ent)) via table lerp
        float t = ent * (1023.0f / LN8_);
        t = fminf(fmaxf(t, 0.f), 1022.999f);
        int it = (int)t;
        float fr = t - (float)it;
        float2 pr = tab_s[it];
        float sig = fmaf(pr.y - pr.x, fr, pr.x);

        // max over d (per pixel)
        red[ty][tx] = sig;
        __syncthreads();
        if (tid < 64) {
            int txl = tid & 31, half = tid >> 5;
            float mv = red[half * 16][txl];
            #pragma unroll
            for (int k = 1; k < 16; ++k) mv = fmaxf(mv, red[half * 16 + k][txl]);
            mv = fmaxf(mv, __shfl_xor(mv, 32));
            if (half == 0) {
                vw_s[txl] = mv;
                out_vw[(b * 4 + (v - 1)) * HW_ + h * W_ + w0 + txl] = mv;
            }
        }
        __syncthreads();
        float vw = vw_s[tx];

        #pragma unroll
        for (int g = 0; g < G_; ++g) simsum[g] = fmaf(sim[g], vw, simsum[g]);
        wsum += vw;
    }

    float wn = __builtin_amdgcn_rcpf(wsum + 1e-6f);
    float* so = out_sim + (size_t)(b * G_) * DHW_ + d * HW_ + p;
    #pragma unroll
    for (int g = 0; g < G_; ++g) so[(size_t)g * DHW_] = simsum[g] * wn;
}

// ---------------- conv3d 3x3x3, pad 1, d-blocked x4 ----------------
// grid (W/32, H/8, B*D/4), block (32, 8)
__global__ __launch_bounds__(256) void k_conv1(
    const float* __restrict__ in,   // [B][8][D][H][W]
    const float* __restrict__ wgt,  // [8][8][27]
    const float* __restrict__ bias, // [8]
    float* __restrict__ out)        // [B][8][D][H][W]
{
    __shared__ float in_s[8][6][10][34];   // 65280 B
    __shared__ float w_t[216 * 8];          // [tap][oc]
    const int tx = threadIdx.x, ty = threadIdx.y;
    const int tid = ty * 32 + tx;
    const int w0 = blockIdx.x * 32;
    const int h0 = blockIdx.y * 8;
    const int z  = blockIdx.z;
    const int b  = z >> 3;
    const int d0 = (z & 7) * 4;

    for (int i = tid; i < 1728; i += 256) {
        int oc = i / 216, tap = i - oc * 216;
        w_t[tap * 8 + oc] = wgt[i];
    }
    for (int i = tid; i < 8 * 6 * 10 * 34; i += 256) {
        int wx = i % 34; int r = i / 34;
        int hy = r % 10; r /= 10;
        int dz = r % 6;  int ic = r / 6;
        int gw = w0 + wx - 1, gh = h0 + hy - 1, gd = d0 + dz - 1;
        float val = 0.f;
        if (gw >= 0 && gw < W_ && gh >= 0 && gh < H_ && gd >= 0 && gd < D_)
            val = in[((b * 8 + ic) * D_ + gd) * HW_ + gh * W_ + gw];
        in_s[ic][dz][hy][wx] = val;
    }
    __syncthreads();

    float acc[4][8];
    #pragma unroll
    for (int dd = 0; dd < 4; ++dd)
        #pragma unroll
        for (int oc = 0; oc < 8; ++oc) acc[dd][oc] = bias[oc];

    #pragma unroll 1
    for (int icdz = 0; icdz < 24; ++icdz) {
        int ic = icdz / 3, dz = icdz - 3 * (icdz / 3);
        #pragma unroll
        for (int hy = 0; hy < 3; ++hy)
            #pragma unroll
            for (int wx = 0; wx < 3; ++wx) {
                int tap = icdz * 9 + hy * 3 + wx;
                float4 wa = *(const float4*)&w_t[tap * 8];
                float4 wb = *(const float4*)&w_t[tap * 8 + 4];
                #pragma unroll
                for (int dd = 0; dd < 4; ++dd) {
                    float vv = in_s[ic][dz + dd][ty + hy][tx + wx];
                    acc[dd][0] = fmaf(vv, wa.x, acc[dd][0]);
                    acc[dd][1] = fmaf(vv, wa.y, acc[dd][1]);
                    acc[dd][2] = fmaf(vv, wa.z, acc[dd][2]);
                    acc[dd][3] = fmaf(vv, wa.w, acc[dd][3]);
                    acc[dd][4] = fmaf(vv, wb.x, acc[dd][4]);
                    acc[dd][5] = fmaf(vv, wb.y, acc[dd][5]);
                    acc[dd][6] = fmaf(vv, wb.z, acc[dd][6]);
                    acc[dd][7] = fmaf(vv, wb.w, acc[dd][7]);
                }
            }
    }

    #pragma unroll
    for (int dd = 0; dd < 4; ++dd)
        #pragma unroll
        for (int oc = 0; oc < 8; ++oc)
            out[((b * 8 + oc) * D_ + d0 + dd) * HW_ + (h0 + ty) * W_ + (w0 + tx)] =
                fmaxf(acc[dd][oc], 0.f);
}

// grid (W/32, H/8, B*D/4), block (32, 8)
__global__ __launch_bounds__(256) void k_conv2(
    const float* __restrict__ in,   // [B][8][D][H][W]
    const float* __restrict__ wgt,  // [1][8][27]
    const float* __restrict__ bias, // [1]
    float* __restrict__ out)        // [B][D][H][W]
{
    __shared__ float in_s[8][6][10][34];
    __shared__ float w_s[216];
    const int tx = threadIdx.x, ty = threadIdx.y;
    const int tid = ty * 32 + tx;
    const int w0 = blockIdx.x * 32;
    const int h0 = blockIdx.y * 8;
    const int z  = blockIdx.z;
    const int b  = z >> 3;
    const int d0 = (z & 7) * 4;

    if (tid < 216) w_s[tid] = wgt[tid];
    for (int i = tid; i < 8 * 6 * 10 * 34; i += 256) {
        int wx = i % 34; int r = i / 34;
        int hy = r % 10; r /= 10;
        int dz = r % 6;  int ic = r / 6;
        int gw = w0 + wx - 1, gh = h0 + hy - 1, gd = d0 + dz - 1;
        float val = 0.f;
        if (gw >= 0 && gw < W_ && gh >= 0 && gh < H_ && gd >= 0 && gd < D_)
            val = in[((b * 8 + ic) * D_ + gd) * HW_ + gh * W_ + gw];
        in_s[ic][dz][hy][wx] = val;
    }
    __syncthreads();

    float acc[4];
    #pragma unroll
    for (int dd = 0; dd < 4; ++dd) acc[dd] = bias[0];

    #pragma unroll 1
    for (int icdz = 0; icdz < 24; ++icdz) {
        int ic = icdz / 3, dz = icdz - 3 * (icdz / 3);
        #pragma unroll
        for (int hy = 0; hy < 3; ++hy)
            #pragma unroll
            for (int wx = 0; wx < 3; ++wx) {
                float wv = w_s[icdz * 9 + hy * 3 + wx];
                #pragma unroll
                for (int dd = 0; dd < 4; ++dd)
                    acc[dd] = fmaf(in_s[ic][dz + dd][ty + hy][tx + wx], wv, acc[dd]);
            }
    }

    #pragma unroll
    for (int dd = 0; dd < 4; ++dd)
        out[(b * D_ + d0 + dd) * HW_ + (h0 + ty) * W_ + (w0 + tx)] = acc[dd];
}

// ---------------- final: softmax over D, depth, confidence ----------------
__global__ __launch_bounds__(256) void k_final(
    const float* __restrict__ pvp,
    const float* __restrict__ depthv,
    float* __restrict__ out_depth,
    float* __restrict__ out_conf)
{
    int i = blockIdx.x * 256 + threadIdx.x;
    if (i >= B_ * HW_) return;
    int b = i / HW_;
    int p = i - b * HW_;

    const float* pp = pvp + b * DHW_ + p;
    const float* dv = depthv + b * DHW_ + p;

    float x[D_];
    float m = -3.4e38f;
    #pragma unroll
    for (int d = 0; d < D_; ++d) { x[d] = pp[d * HW_]; m = fmaxf(m, x[d]); }
    float s = 0.f;
    #pragma unroll
    for (int d = 0; d < D_; ++d) { x[d] = exp2f((x[d] - m) * LOG2E_); s += x[d]; }
    float inv = 1.f / s;

    float dep = 0.f, fd = 0.f;
    #pragma unroll
    for (int d = 0; d < D_; ++d) {
        float pv = x[d] * inv;
        x[d] = pv;
        dep = fmaf(pv, dv[d * HW_], dep);
        fd  = fmaf(pv, (float)d, fd);
    }
    int di = (int)fd;
    di = di < 0 ? 0 : (di > D_ - 1 ? D_ - 1 : di);
    float conf = 0.f;
    #pragma unroll
    for (int k = 0; k < 4; ++k) {
        int idx = di - 1 + k;
        if (idx >= 0 && idx < D_) conf += x[idx];
    }
    out_depth[i] = dep;
    out_conf[i]  = conf;
}

// ---------------- launch ----------------
extern "C" void kernel_launch(void* const* d_in, const int* in_sizes, int n_in,
                              void* d_out, int out_size, void* d_ws, size_t ws_size,
                              hipStream_t stream) {
    const float* feat   = (const float*)d_in[0];
    const float* pm     = (const float*)d_in[1];
    const float* depthv = (const float*)d_in[2];
    const float* reg_w1 = (const float*)d_in[3];
    const float* reg_b1 = (const float*)d_in[4];
    const float* reg_w2 = (const float*)d_in[5];
    const float* reg_b2 = (const float*)d_in[6];
    const float* pw_w1  = (const float*)d_in[7];
    const float* pw_b1  = (const float*)d_in[8];
    const float* pw_w2  = (const float*)d_in[9];
    const float* pw_b2  = (const float*)d_in[10];
    const float* pw_w3  = (const float*)d_in[11];
    const float* pw_b3  = (const float*)d_in[12];

    float* out = (float*)d_out;
    float* out_depth = out;
    float* out_conf  = out + B_*HW_;
    float* out_vw    = out + 2*B_*HW_;
    float* out_pvp   = out_vw + B_*4*HW_;
    float* out_sim   = out_pvp + B_*DHW_;

    float* ws      = (float*)d_ws;
    float* proj_ws = ws;            // 96
    float* tabw    = ws + 128;      // 1024
    float* featT   = ws + 2048;     // 6.55M floats (VB*HW*32)
    float* hid     = ws + 2048;     // 10.49M floats, overwrites featT after k_main

    hipLaunchKernelGGL(k_proj, dim3(1), dim3(1024), 0, stream,
                       pm, pw_w1, pw_b1, pw_w2, pw_b2, pw_w3, pw_b3, proj_ws, tabw);

    hipLaunchKernelGGL(k_transpose, dim3(HW_/32, V_*B_), dim3(32, 32), 0, stream,
                       feat, featT);

    hipLaunchKernelGGL(k_main, dim3(W_/32, H_, B_), dim3(32, 32), 0, stream,
                       featT, depthv, proj_ws, tabw, out_vw, out_sim);

    hipLaunchKernelGGL(k_conv1, dim3(W_/32, H_/8, B_*D_/4), dim3(32, 8), 0, stream,
                       out_sim, reg_w1, reg_b1, hid);

    hipLaunchKernelGGL(k_conv2, dim3(W_/32, H_/8, B_*D_/4), dim3(32, 8), 0, stream,
                       hid, reg_w2, reg_b2, out_pvp);

    hipLaunchKernelGGL(k_final, dim3((B_*HW_ + 255)/256), dim3(256), 0, stream,
                       out_pvp, depthv, out_depth, out_conf);
}

// Round 3
// 562.396 us; speedup vs baseline: 1.2665x; 1.2665x over previous
//
#include <hip/hip_runtime.h>
#include <hip/hip_bf16.h>

#define V_  5
#define B_  2
#define C_  32
#define H_  128
#define W_  160
#define D_  32
#define G_  8
#define HW_  (H_*W_)
#define DHW_ (D_*HW_)

#define LOG2E_ 1.4426950408889634f
#define LN2_   0.6931471805599453f
#define LN8_   2.0794415416798357f

// ws layout (floats): [0..95] proj | [128..1151] mlp table | [2048 ...] featT (26.2MB) then hid (41.9MB, overwrites featT)

// ---------------- projection + MLP table setup ----------------

__device__ inline void combine_mat(const float* m, float out[4][4]) {
    const float* ext = m;
    const float* K   = m + 16;
    for (int r = 0; r < 4; ++r)
        for (int c = 0; c < 4; ++c)
            out[r][c] = ext[r*4 + c];
    for (int r = 0; r < 3; ++r)
        for (int c = 0; c < 4; ++c) {
            float s = 0.f;
            for (int k = 0; k < 3; ++k) s += K[r*4 + k] * ext[k*4 + c];
            out[r][c] = s;
        }
}

__device__ inline void invert4(const float Ain[4][4], float Inv[4][4]) {
    float A[4][4];
    for (int r = 0; r < 4; ++r)
        for (int c = 0; c < 4; ++c) {
            A[r][c]   = Ain[r][c];
            Inv[r][c] = (r == c) ? 1.f : 0.f;
        }
    for (int k = 0; k < 4; ++k) {
        int p = k; float best = fabsf(A[k][k]);
        for (int r = k + 1; r < 4; ++r) {
            float v = fabsf(A[r][k]);
            if (v > best) { best = v; p = r; }
        }
        if (p != k) {
            for (int j = 0; j < 4; ++j) {
                float t = A[k][j]; A[k][j] = A[p][j]; A[p][j] = t;
                t = Inv[k][j]; Inv[k][j] = Inv[p][j]; Inv[p][j] = t;
            }
        }
        float dinv = 1.f / A[k][k];
        for (int j = 0; j < 4; ++j) { A[k][j] *= dinv; Inv[k][j] *= dinv; }
        for (int r = 0; r < 4; ++r) {
            if (r == k) continue;
            float f = A[r][k];
            for (int j = 0; j < 4; ++j) {
                A[r][j]  -= f * A[k][j];
                Inv[r][j] -= f * Inv[k][j];
            }
        }
    }
}

__global__ __launch_bounds__(1024) void k_proj(
    const float* __restrict__ pm,
    const float* __restrict__ pw_w1, const float* __restrict__ pw_b1,
    const float* __restrict__ pw_w2, const float* __restrict__ pw_b2,
    const float* __restrict__ pw_w3, const float* __restrict__ pw_b3,
    float* __restrict__ proj_ws, float* __restrict__ tabw)
{
    int tid = threadIdx.x;
    if (tid < B_) {
        int b = tid;
        float C0[4][4], C0inv[4][4];
        combine_mat(pm + (b * V_ + 0) * 32, C0);
        invert4(C0, C0inv);
        for (int v = 1; v < V_; ++v) {
            float Cv[4][4];
            combine_mat(pm + (b * V_ + v) * 32, Cv);
            float* o = proj_ws + (b * 4 + (v - 1)) * 12;
            for (int r = 0; r < 3; ++r)
                for (int c = 0; c < 4; ++c) {
                    float s = 0.f;
                    for (int k = 0; k < 4; ++k) s += Cv[r][k] * C0inv[k][c];
                    o[r*4 + c] = s;
                }
        }
    }
    // MLP sigmoid table over ent in [0, ln 8]
    float ent = (float)tid * (LN8_ / 1023.0f);
    float h2[8];
    #pragma unroll
    for (int j = 0; j < 8; ++j) h2[j] = pw_b2[j];
    for (int k = 0; k < 16; ++k) {
        float h1 = fmaxf(ent * pw_w1[k] + pw_b1[k], 0.f);
        #pragma unroll
        for (int j = 0; j < 8; ++j) h2[j] += pw_w2[j*16 + k] * h1;
    }
    float o3 = pw_b3[0];
    #pragma unroll
    for (int j = 0; j < 8; ++j) o3 += pw_w3[j] * fmaxf(h2[j], 0.f);
    tabw[tid] = 1.f / (1.f + expf(-o3));
}

// ---------------- feature transpose: [V][B][C][H][W] -> [VB][HW][C] ----------------
__global__ __launch_bounds__(1024) void k_transpose(
    const float* __restrict__ in, float* __restrict__ out)
{
    __shared__ float s[32][33];
    const int tx = threadIdx.x, ty = threadIdx.y;
    const int hw0 = blockIdx.x * 32;
    const int vb  = blockIdx.y;
    s[ty][tx] = in[(vb * 32 + ty) * HW_ + hw0 + tx];
    __syncthreads();
    out[(vb * HW_ + hw0 + ty) * 32 + tx] = s[tx][ty];
}

// ---------------- main fused kernel ----------------
// grid (W/32, H, B), block 1024 linear.
// wave wv (0..15) covers pixels {2wv, 2wv+1} x all 32 depths.
// lane = j*32 + d  (j = pixel-within-wave, d = depth)
__global__ __launch_bounds__(1024) void k_main(
    const float* __restrict__ featT,    // [VB][HW][32]
    const float* __restrict__ depthv,   // [B][D][H][W]
    const float* __restrict__ proj_ws,
    const float* __restrict__ tabw,     // 1024 sigmoid table
    float* __restrict__ out_vw,         // [B][4][H][W]
    float* __restrict__ out_sim)        // [B][G][D][H][W]
{
    const int tid = threadIdx.x;
    const int wv   = tid >> 6;
    const int lane = tid & 63;
    const int j    = lane >> 5;
    const int d    = lane & 31;
    const int pxl  = wv * 2 + j;         // 0..31
    const int w0 = blockIdx.x * 32;
    const int h  = blockIdx.y;
    const int b  = blockIdx.z;
    const int w  = w0 + pxl;
    const int p  = h * W_ + w;

    __shared__ float tab_s[1024];
    __shared__ float proj_s[48];
    __shared__ float s_sim[G_][32][33];

    tab_s[tid] = tabw[tid];
    if (tid < 48) proj_s[tid] = proj_ws[b * 48 + tid];
    __syncthreads();

    // ref fragment (view 0) into registers: 8 float4 = 32 ch (broadcast across d-lanes)
    const float4* rp = (const float4*)(featT + ((size_t)b * HW_ + p) * 32);
    float4 refv[8];
    #pragma unroll
    for (int cc = 0; cc < 8; ++cc) refv[cc] = rp[cc];

    const float depth = depthv[(b * D_ + d) * HW_ + p];
    const float xf = (float)w, yf = (float)h;

    float simsum[G_];
    #pragma unroll
    for (int g = 0; g < G_; ++g) simsum[g] = 0.f;
    float wsum = 0.f;

    for (int v = 1; v < V_; ++v) {
        const float* P = &proj_s[(v - 1) * 12];
        float px = (P[0]*xf + P[1]*yf + P[2])  * depth + P[3];
        float py = (P[4]*xf + P[5]*yf + P[6])  * depth + P[7];
        float pz = (P[8]*xf + P[9]*yf + P[10]) * depth + P[11];
        float rz = __builtin_amdgcn_rcpf(pz);
        float xs = px * rz;
        float ys = py * rz;

        float x0 = floorf(xs), y0 = floorf(ys);
        float wx1 = xs - x0,  wy1 = ys - y0;
        float wx0 = 1.f - wx1, wy0 = 1.f - wy1;

        bool vx0 = (x0 >= 0.f)     && (x0 <= (float)(W_-1));
        bool vx1 = (x0+1.f >= 0.f) && (x0+1.f <= (float)(W_-1));
        bool vy0 = (y0 >= 0.f)     && (y0 <= (float)(H_-1));
        bool vy1 = (y0+1.f >= 0.f) && (y0+1.f <= (float)(H_-1));

        int xc0 = (int)fminf(fmaxf(x0,     0.f), (float)(W_-1));
        int xc1 = (int)fminf(fmaxf(x0+1.f, 0.f), (float)(W_-1));
        int yc0 = (int)fminf(fmaxf(y0,     0.f), (float)(H_-1));
        int yc1 = (int)fminf(fmaxf(y0+1.f, 0.f), (float)(H_-1));

        float w00 = (vx0 && vy0) ? (wx0 * wy0) : 0.f;
        float w01 = (vx1 && vy0) ? (wx1 * wy0) : 0.f;
        float w10 = (vx0 && vy1) ? (wx0 * wy1) : 0.f;
        float w11 = (vx1 && vy1) ? (wx1 * wy1) : 0.f;

        const float* vbp = featT + (size_t)(v * B_ + b) * HW_ * 32;
        const float4* p00 = (const float4*)(vbp + (yc0 * W_ + xc0) * 32);
        const float4* p01 = (const float4*)(vbp + (yc0 * W_ + xc1) * 32);
        const float4* p10 = (const float4*)(vbp + (yc1 * W_ + xc0) * 32);
        const float4* p11 = (const float4*)(vbp + (yc1 * W_ + xc1) * 32);

        float sim[G_];
        #pragma unroll
        for (int cc = 0; cc < 8; ++cc) {
            float4 a = p00[cc], bq = p01[cc], cq = p10[cc], dq = p11[cc];
            float vx = fmaf(dq.x, w11, fmaf(cq.x, w10, fmaf(bq.x, w01, a.x * w00)));
            float vy = fmaf(dq.y, w11, fmaf(cq.y, w10, fmaf(bq.y, w01, a.y * w00)));
            float vz = fmaf(dq.z, w11, fmaf(cq.z, w10, fmaf(bq.z, w01, a.z * w00)));
            float vw4= fmaf(dq.w, w11, fmaf(cq.w, w10, fmaf(bq.w, w01, a.w * w00)));
            float4 rv = refv[cc];
            float dot = fmaf(vx, rv.x, fmaf(vy, rv.y, fmaf(vz, rv.z, vw4 * rv.w)));
            sim[cc] = dot * 0.25f;
        }

        // entropy of softmax(sim): ent = m + ln(es) - (sum e*sim)/es
        float m = sim[0];
        #pragma unroll
        for (int g = 1; g < G_; ++g) m = fmaxf(m, sim[g]);
        float es = 0.f, edot = 0.f;
        #pragma unroll
        for (int g = 0; g < G_; ++g) {
            float e = exp2f((sim[g] - m) * LOG2E_);
            es += e;
            edot = fmaf(e, sim[g], edot);
        }
        float inv_es = __builtin_amdgcn_rcpf(es);
        float ent = m + log2f(es) * LN2_ - edot * inv_es;

        // sigmoid(MLP(ent)) via table lerp
        float t = ent * (1023.0f / LN8_);
        t = fminf(fmaxf(t, 0.f), 1022.999f);
        int it = (int)t;
        float fr = t - (float)it;
        float lo = tab_s[it], hi = tab_s[it + 1];
        float sig = fmaf(hi - lo, fr, lo);

        // max over the 32 depth lanes (within each 32-lane half) — no barrier
        float mv = sig;
        #pragma unroll
        for (int k = 16; k >= 1; k >>= 1)
            mv = fmaxf(mv, __shfl_xor(mv, k, 64));
        if (d == 0)
            out_vw[(b * 4 + (v - 1)) * HW_ + p] = mv;

        #pragma unroll
        for (int g = 0; g < G_; ++g) simsum[g] = fmaf(sim[g], mv, simsum[g]);
        wsum += mv;
    }

    float wn = __builtin_amdgcn_rcpf(wsum + 1e-6f);
    // stage d-major results into LDS, then write w-coalesced
    #pragma unroll
    for (int g = 0; g < G_; ++g) s_sim[g][d][pxl] = simsum[g] * wn;
    __syncthreads();

    const int tx = tid & 31;       // w
    const int ty = tid >> 5;       // d
    float* so = out_sim + (size_t)b * G_ * DHW_ + ty * HW_ + h * W_ + w0 + tx;
    #pragma unroll
    for (int g = 0; g < G_; ++g) so[(size_t)g * DHW_] = s_sim[g][ty][tx];
}

// ---------------- conv3d 3x3x3, pad 1, d-blocked x4, ic-chunked x2 ----------------
// grid (W/32, H/8, B*D/4), block (32, 8)
__global__ __launch_bounds__(256) void k_conv1(
    const float* __restrict__ in,   // [B][8][D][H][W]
    const float* __restrict__ wgt,  // [8][8][27]
    const float* __restrict__ bias, // [8]
    float* __restrict__ out)        // [B][8][D][H][W]
{
    __shared__ float in_s[4][6][10][34];   // 32640 B
    __shared__ float w_t[216 * 8];          // [tap][oc], 6912 B
    const int tx = threadIdx.x, ty = threadIdx.y;
    const int tid = ty * 32 + tx;
    const int w0 = blockIdx.x * 32;
    const int h0 = blockIdx.y * 8;
    const int z  = blockIdx.z;
    const int b  = z >> 3;
    const int d0 = (z & 7) * 4;

    for (int i = tid; i < 1728; i += 256) {
        int oc = i / 216, tap = i - oc * 216;
        w_t[tap * 8 + oc] = wgt[i];
    }

    float acc[4][8];
    #pragma unroll
    for (int dd = 0; dd < 4; ++dd)
        #pragma unroll
        for (int oc = 0; oc < 8; ++oc) acc[dd][oc] = bias[oc];

    for (int ch = 0; ch < 2; ++ch) {
        if (ch) __syncthreads();
        for (int i = tid; i < 4 * 6 * 10 * 34; i += 256) {
            int wx = i % 34; int r = i / 34;
            int hy = r % 10; r /= 10;
            int dz = r % 6;  int icl = r / 6;
            int ic = ch * 4 + icl;
            int gw = w0 + wx - 1, gh = h0 + hy - 1, gd = d0 + dz - 1;
            float val = 0.f;
            if (gw >= 0 && gw < W_ && gh >= 0 && gh < H_ && gd >= 0 && gd < D_)
                val = in[((b * 8 + ic) * D_ + gd) * HW_ + gh * W_ + gw];
            in_s[icl][dz][hy][wx] = val;
        }
        __syncthreads();

        #pragma unroll 1
        for (int icdz = 0; icdz < 12; ++icdz) {
            int icl = icdz / 3, dz = icdz - 3 * (icdz / 3);
            #pragma unroll
            for (int hy = 0; hy < 3; ++hy)
                #pragma unroll
                for (int wx = 0; wx < 3; ++wx) {
                    int tap = (ch * 12 + icdz) * 9 + hy * 3 + wx;
                    float4 wa = *(const float4*)&w_t[tap * 8];
                    float4 wb = *(const float4*)&w_t[tap * 8 + 4];
                    #pragma unroll
                    for (int dd = 0; dd < 4; ++dd) {
                        float vv = in_s[icl][dz + dd][ty + hy][tx + wx];
                        acc[dd][0] = fmaf(vv, wa.x, acc[dd][0]);
                        acc[dd][1] = fmaf(vv, wa.y, acc[dd][1]);
                        acc[dd][2] = fmaf(vv, wa.z, acc[dd][2]);
                        acc[dd][3] = fmaf(vv, wa.w, acc[dd][3]);
                        acc[dd][4] = fmaf(vv, wb.x, acc[dd][4]);
                        acc[dd][5] = fmaf(vv, wb.y, acc[dd][5]);
                        acc[dd][6] = fmaf(vv, wb.z, acc[dd][6]);
                        acc[dd][7] = fmaf(vv, wb.w, acc[dd][7]);
                    }
                }
        }
    }

    #pragma unroll
    for (int dd = 0; dd < 4; ++dd)
        #pragma unroll
        for (int oc = 0; oc < 8; ++oc)
            out[((b * 8 + oc) * D_ + d0 + dd) * HW_ + (h0 + ty) * W_ + (w0 + tx)] =
                fmaxf(acc[dd][oc], 0.f);
}

// grid (W/32, H/8, B*D/4), block (32, 8)
__global__ __launch_bounds__(256) void k_conv2(
    const float* __restrict__ in,   // [B][8][D][H][W]
    const float* __restrict__ wgt,  // [1][8][27]
    const float* __restrict__ bias, // [1]
    float* __restrict__ out)        // [B][D][H][W]
{
    __shared__ float in_s[4][6][10][34];
    __shared__ float w_s[216];
    const int tx = threadIdx.x, ty = threadIdx.y;
    const int tid = ty * 32 + tx;
    const int w0 = blockIdx.x * 32;
    const int h0 = blockIdx.y * 8;
    const int z  = blockIdx.z;
    const int b  = z >> 3;
    const int d0 = (z & 7) * 4;

    if (tid < 216) w_s[tid] = wgt[tid];

    float acc[4];
    #pragma unroll
    for (int dd = 0; dd < 4; ++dd) acc[dd] = bias[0];

    for (int ch = 0; ch < 2; ++ch) {
        if (ch) __syncthreads();
        for (int i = tid; i < 4 * 6 * 10 * 34; i += 256) {
            int wx = i % 34; int r = i / 34;
            int hy = r % 10; r /= 10;
            int dz = r % 6;  int icl = r / 6;
            int ic = ch * 4 + icl;
            int gw = w0 + wx - 1, gh = h0 + hy - 1, gd = d0 + dz - 1;
            float val = 0.f;
            if (gw >= 0 && gw < W_ && gh >= 0 && gh < H_ && gd >= 0 && gd < D_)
                val = in[((b * 8 + ic) * D_ + gd) * HW_ + gh * W_ + gw];
            in_s[icl][dz][hy][wx] = val;
        }
        __syncthreads();

        #pragma unroll 1
        for (int icdz = 0; icdz < 12; ++icdz) {
            int icl = icdz / 3, dz = icdz - 3 * (icdz / 3);
            #pragma unroll
            for (int hy = 0; hy < 3; ++hy)
                #pragma unroll
                for (int wx = 0; wx < 3; ++wx) {
                    float wv = w_s[(ch * 12 + icdz) * 9 + hy * 3 + wx];
                    #pragma unroll
                    for (int dd = 0; dd < 4; ++dd)
                        acc[dd] = fmaf(in_s[icl][dz + dd][ty + hy][tx + wx], wv, acc[dd]);
                }
        }
    }

    #pragma unroll
    for (int dd = 0; dd < 4; ++dd)
        out[(b * D_ + d0 + dd) * HW_ + (h0 + ty) * W_ + (w0 + tx)] = acc[dd];
}

// ---------------- final: softmax over D, depth, confidence ----------------
__global__ __launch_bounds__(256) void k_final(
    const float* __restrict__ pvp,
    const float* __restrict__ depthv,
    float* __restrict__ out_depth,
    float* __restrict__ out_conf)
{
    int i = blockIdx.x * 256 + threadIdx.x;
    if (i >= B_ * HW_) return;
    int b = i / HW_;
    int p = i - b * HW_;

    const float* pp = pvp + b * DHW_ + p;
    const float* dv = depthv + b * DHW_ + p;

    float x[D_];
    float m = -3.4e38f;
    #pragma unroll
    for (int d = 0; d < D_; ++d) { x[d] = pp[d * HW_]; m = fmaxf(m, x[d]); }
    float s = 0.f;
    #pragma unroll
    for (int d = 0; d < D_; ++d) { x[d] = exp2f((x[d] - m) * LOG2E_); s += x[d]; }
    float inv = 1.f / s;

    float dep = 0.f, fd = 0.f;
    #pragma unroll
    for (int d = 0; d < D_; ++d) {
        float pv = x[d] * inv;
        x[d] = pv;
        dep = fmaf(pv, dv[d * HW_], dep);
        fd  = fmaf(pv, (float)d, fd);
    }
    int di = (int)fd;
    di = di < 0 ? 0 : (di > D_ - 1 ? D_ - 1 : di);
    float conf = 0.f;
    #pragma unroll
    for (int k = 0; k < 4; ++k) {
        int idx = di - 1 + k;
        if (idx >= 0 && idx < D_) conf += x[idx];
    }
    out_depth[i] = dep;
    out_conf[i]  = conf;
}

// ---------------- launch ----------------
extern "C" void kernel_launch(void* const* d_in, const int* in_sizes, int n_in,
                              void* d_out, int out_size, void* d_ws, size_t ws_size,
                              hipStream_t stream) {
    const float* feat   = (const float*)d_in[0];
    const float* pm     = (const float*)d_in[1];
    const float* depthv = (const float*)d_in[2];
    const float* reg_w1 = (const float*)d_in[3];
    const float* reg_b1 = (const float*)d_in[4];
    const float* reg_w2 = (const float*)d_in[5];
    const float* reg_b2 = (const float*)d_in[6];
    const float* pw_w1  = (const float*)d_in[7];
    const float* pw_b1  = (const float*)d_in[8];
    const float* pw_w2  = (const float*)d_in[9];
    const float* pw_b2  = (const float*)d_in[10];
    const float* pw_w3  = (const float*)d_in[11];
    const float* pw_b3  = (const float*)d_in[12];

    float* out = (float*)d_out;
    float* out_depth = out;
    float* out_conf  = out + B_*HW_;
    float* out_vw    = out + 2*B_*HW_;
    float* out_pvp   = out_vw + B_*4*HW_;
    float* out_sim   = out_pvp + B_*DHW_;

    float* ws      = (float*)d_ws;
    float* proj_ws = ws;            // 96
    float* tabw    = ws + 128;      // 1024
    float* featT   = ws + 2048;     // 6.55M floats (VB*HW*32)
    float* hid     = ws + 2048;     // 10.49M floats, overwrites featT after k_main

    hipLaunchKernelGGL(k_proj, dim3(1), dim3(1024), 0, stream,
                       pm, pw_w1, pw_b1, pw_w2, pw_b2, pw_w3, pw_b3, proj_ws, tabw);

    hipLaunchKernelGGL(k_transpose, dim3(HW_/32, V_*B_), dim3(32, 32), 0, stream,
                       feat, featT);

    hipLaunchKernelGGL(k_main, dim3(W_/32, H_, B_), dim3(1024), 0, stream,
                       featT, depthv, proj_ws, tabw, out_vw, out_sim);

    hipLaunchKernelGGL(k_conv1, dim3(W_/32, H_/8, B_*D_/4), dim3(32, 8), 0, stream,
                       out_sim, reg_w1, reg_b1, hid);

    hipLaunchKernelGGL(k_conv2, dim3(W_/32, H_/8, B_*D_/4), dim3(32, 8), 0, stream,
                       hid, reg_w2, reg_b2, out_pvp);

    hipLaunchKernelGGL(k_final, dim3((B_*HW_ + 255)/256), dim3(256), 0, stream,
                       out_pvp, depthv, out_depth, out_conf);
}

// Round 4
// 339.070 us; speedup vs baseline: 2.1007x; 1.6586x over previous
//
#include <hip/hip_runtime.h>
#include <hip/hip_bf16.h>
#include <hip/hip_fp16.h>

#define V_  5
#define B_  2
#define C_  32
#define H_  128
#define W_  160
#define D_  32
#define G_  8
#define HW_  (H_*W_)
#define DHW_ (D_*HW_)

#define LOG2E_ 1.4426950408889634f
#define LN2_   0.6931471805599453f
#define LN8_   2.0794415416798357f

typedef _Float16 half8 __attribute__((ext_vector_type(8)));

// ws layout (floats): [0..95] proj | [128..1151] mlp table | [2048 ...] featT (fp16, 13.1MB) / hid (fp32 41.9MB, overwrites featT after k_main)

// ---------------- projection + MLP table setup ----------------

__device__ inline void combine_mat(const float* m, float out[4][4]) {
    const float* ext = m;
    const float* K   = m + 16;
    for (int r = 0; r < 4; ++r)
        for (int c = 0; c < 4; ++c)
            out[r][c] = ext[r*4 + c];
    for (int r = 0; r < 3; ++r)
        for (int c = 0; c < 4; ++c) {
            float s = 0.f;
            for (int k = 0; k < 3; ++k) s += K[r*4 + k] * ext[k*4 + c];
            out[r][c] = s;
        }
}

__device__ inline void invert4(const float Ain[4][4], float Inv[4][4]) {
    float A[4][4];
    for (int r = 0; r < 4; ++r)
        for (int c = 0; c < 4; ++c) {
            A[r][c]   = Ain[r][c];
            Inv[r][c] = (r == c) ? 1.f : 0.f;
        }
    for (int k = 0; k < 4; ++k) {
        int p = k; float best = fabsf(A[k][k]);
        for (int r = k + 1; r < 4; ++r) {
            float v = fabsf(A[r][k]);
            if (v > best) { best = v; p = r; }
        }
        if (p != k) {
            for (int j = 0; j < 4; ++j) {
                float t = A[k][j]; A[k][j] = A[p][j]; A[p][j] = t;
                t = Inv[k][j]; Inv[k][j] = Inv[p][j]; Inv[p][j] = t;
            }
        }
        float dinv = 1.f / A[k][k];
        for (int j = 0; j < 4; ++j) { A[k][j] *= dinv; Inv[k][j] *= dinv; }
        for (int r = 0; r < 4; ++r) {
            if (r == k) continue;
            float f = A[r][k];
            for (int j = 0; j < 4; ++j) {
                A[r][j]  -= f * A[k][j];
                Inv[r][j] -= f * Inv[k][j];
            }
        }
    }
}

__global__ __launch_bounds__(1024) void k_proj(
    const float* __restrict__ pm,
    const float* __restrict__ pw_w1, const float* __restrict__ pw_b1,
    const float* __restrict__ pw_w2, const float* __restrict__ pw_b2,
    const float* __restrict__ pw_w3, const float* __restrict__ pw_b3,
    float* __restrict__ proj_ws, float* __restrict__ tabw)
{
    int tid = threadIdx.x;
    if (tid < B_) {
        int b = tid;
        float C0[4][4], C0inv[4][4];
        combine_mat(pm + (b * V_ + 0) * 32, C0);
        invert4(C0, C0inv);
        for (int v = 1; v < V_; ++v) {
            float Cv[4][4];
            combine_mat(pm + (b * V_ + v) * 32, Cv);
            float* o = proj_ws + (b * 4 + (v - 1)) * 12;
            for (int r = 0; r < 3; ++r)
                for (int c = 0; c < 4; ++c) {
                    float s = 0.f;
                    for (int k = 0; k < 4; ++k) s += Cv[r][k] * C0inv[k][c];
                    o[r*4 + c] = s;
                }
        }
    }
    // MLP sigmoid table over ent in [0, ln 8]
    float ent = (float)tid * (LN8_ / 1023.0f);
    float h2[8];
    #pragma unroll
    for (int j = 0; j < 8; ++j) h2[j] = pw_b2[j];
    for (int k = 0; k < 16; ++k) {
        float h1 = fmaxf(ent * pw_w1[k] + pw_b1[k], 0.f);
        #pragma unroll
        for (int j = 0; j < 8; ++j) h2[j] += pw_w2[j*16 + k] * h1;
    }
    float o3 = pw_b3[0];
    #pragma unroll
    for (int j = 0; j < 8; ++j) o3 += pw_w3[j] * fmaxf(h2[j], 0.f);
    tabw[tid] = 1.f / (1.f + expf(-o3));
}

// ---------------- feature transpose: [V][B][C][H][W] f32 -> [VB][HW][C] fp16 ----------------
__global__ __launch_bounds__(1024) void k_transpose(
    const float* __restrict__ in, _Float16* __restrict__ out)
{
    __shared__ float s[32][33];
    const int tx = threadIdx.x, ty = threadIdx.y;
    const int hw0 = blockIdx.x * 32;
    const int vb  = blockIdx.y;
    s[ty][tx] = in[(vb * 32 + ty) * HW_ + hw0 + tx];
    __syncthreads();
    out[((size_t)vb * HW_ + hw0 + ty) * 32 + tx] = (_Float16)s[tx][ty];
}

// ---------------- main fused kernel ----------------
// grid (W/32, H, B), block 1024 linear.
// wave wv (0..15) covers pixels {2wv, 2wv+1} x all 32 depths.
// lane = j*32 + d
__global__ __launch_bounds__(1024) void k_main(
    const _Float16* __restrict__ featT, // [VB][HW][32] fp16
    const float* __restrict__ depthv,   // [B][D][H][W]
    const float* __restrict__ proj_ws,
    const float* __restrict__ tabw,
    float* __restrict__ out_vw,         // [B][4][H][W]
    float* __restrict__ out_sim)        // [B][G][D][H][W]
{
    const int tid = threadIdx.x;
    const int wv   = tid >> 6;
    const int lane = tid & 63;
    const int j    = lane >> 5;
    const int d    = lane & 31;
    const int pxl  = wv * 2 + j;
    const int w0 = blockIdx.x * 32;
    const int h  = blockIdx.y;
    const int b  = blockIdx.z;
    const int w  = w0 + pxl;
    const int p  = h * W_ + w;

    __shared__ float tab_s[1024];
    __shared__ float proj_s[48];
    __shared__ float s_sim[G_][32][33];

    tab_s[tid] = tabw[tid];
    if (tid < 48) proj_s[tid] = proj_ws[b * 48 + tid];
    __syncthreads();

    // ref fragment (view 0) -> fp32 registers
    const half8* rp = (const half8*)(featT + ((size_t)b * HW_ + p) * 32);
    float refc[32];
    #pragma unroll
    for (int cc = 0; cc < 4; ++cc) {
        half8 rv = rp[cc];
        #pragma unroll
        for (int k = 0; k < 8; ++k) refc[cc * 8 + k] = (float)rv[k];
    }

    const float depth = depthv[(b * D_ + d) * HW_ + p];
    const float xf = (float)w, yf = (float)h;

    float simsum[G_];
    #pragma unroll
    for (int g = 0; g < G_; ++g) simsum[g] = 0.f;
    float wsum = 0.f;

    for (int v = 1; v < V_; ++v) {
        const float* P = &proj_s[(v - 1) * 12];
        float px = (P[0]*xf + P[1]*yf + P[2])  * depth + P[3];
        float py = (P[4]*xf + P[5]*yf + P[6])  * depth + P[7];
        float pz = (P[8]*xf + P[9]*yf + P[10]) * depth + P[11];
        float rz = __builtin_amdgcn_rcpf(pz);
        float xs = px * rz;
        float ys = py * rz;

        // snap near-integer coords (<=1e-4 px shift; makes zero-weight rows exact)
        float xr = rintf(xs);
        float yr = rintf(ys);
        xs = (fabsf(xs - xr) < 1e-4f) ? xr : xs;
        ys = (fabsf(ys - yr) < 1e-4f) ? yr : ys;

        float x0 = floorf(xs), y0 = floorf(ys);
        float wx1 = xs - x0,  wy1 = ys - y0;
        float wx0 = 1.f - wx1, wy0 = 1.f - wy1;

        bool vx0 = (x0 >= 0.f)     && (x0 <= (float)(W_-1));
        bool vx1 = (x0+1.f >= 0.f) && (x0+1.f <= (float)(W_-1));
        bool vy0 = (y0 >= 0.f)     && (y0 <= (float)(H_-1));
        bool vy1 = (y0+1.f >= 0.f) && (y0+1.f <= (float)(H_-1));

        int xc0 = (int)fminf(fmaxf(x0,     0.f), (float)(W_-1));
        int xc1 = (int)fminf(fmaxf(x0+1.f, 0.f), (float)(W_-1));
        int yc0 = (int)fminf(fmaxf(y0,     0.f), (float)(H_-1));
        int yc1 = (int)fminf(fmaxf(y0+1.f, 0.f), (float)(H_-1));

        float w00 = (vx0 && vy0) ? (wx0 * wy0) : 0.f;
        float w01 = (vx1 && vy0) ? (wx1 * wy0) : 0.f;
        float w10 = (vx0 && vy1) ? (wx0 * wy1) : 0.f;
        float w11 = (vx1 && vy1) ? (wx1 * wy1) : 0.f;

        const _Float16* vbp = featT + (size_t)(v * B_ + b) * HW_ * 32;

        float sim[G_];
        #pragma unroll
        for (int g = 0; g < G_; ++g) sim[g] = 0.f;

        bool top = __any(w00 > 0.f || w01 > 0.f);
        bool bot = __any(w10 > 0.f || w11 > 0.f);

        if (top) {
            const half8* t00 = (const half8*)(vbp + (size_t)(yc0 * W_ + xc0) * 32);
            const half8* t01 = (const half8*)(vbp + (size_t)(yc0 * W_ + xc1) * 32);
            #pragma unroll
            for (int cc = 0; cc < 4; ++cc) {
                half8 a = t00[cc], bb = t01[cc];
                #pragma unroll
                for (int k = 0; k < 8; ++k) {
                    float fv = fmaf((float)bb[k], w01, (float)a[k] * w00);
                    int g = cc * 2 + (k >> 2);
                    sim[g] = fmaf(fv, refc[cc * 8 + k], sim[g]);
                }
            }
        }
        if (bot) {
            const half8* t10 = (const half8*)(vbp + (size_t)(yc1 * W_ + xc0) * 32);
            const half8* t11 = (const half8*)(vbp + (size_t)(yc1 * W_ + xc1) * 32);
            #pragma unroll
            for (int cc = 0; cc < 4; ++cc) {
                half8 cq = t10[cc], dq = t11[cc];
                #pragma unroll
                for (int k = 0; k < 8; ++k) {
                    float fv = fmaf((float)dq[k], w11, (float)cq[k] * w10);
                    int g = cc * 2 + (k >> 2);
                    sim[g] = fmaf(fv, refc[cc * 8 + k], sim[g]);
                }
            }
        }

        #pragma unroll
        for (int g = 0; g < G_; ++g) sim[g] *= 0.25f;

        // entropy of softmax(sim)
        float m = sim[0];
        #pragma unroll
        for (int g = 1; g < G_; ++g) m = fmaxf(m, sim[g]);
        float es = 0.f, edot = 0.f;
        #pragma unroll
        for (int g = 0; g < G_; ++g) {
            float e = exp2f((sim[g] - m) * LOG2E_);
            es += e;
            edot = fmaf(e, sim[g], edot);
        }
        float inv_es = __builtin_amdgcn_rcpf(es);
        float ent = m + log2f(es) * LN2_ - edot * inv_es;

        // sigmoid(MLP(ent)) via table lerp
        float t = ent * (1023.0f / LN8_);
        t = fminf(fmaxf(t, 0.f), 1022.999f);
        int it = (int)t;
        float fr = t - (float)it;
        float lo = tab_s[it], hi = tab_s[it + 1];
        float sig = fmaf(hi - lo, fr, lo);

        // max over the 32 depth lanes (per pixel) — shuffle, no barrier
        float mv = sig;
        #pragma unroll
        for (int k = 16; k >= 1; k >>= 1)
            mv = fmaxf(mv, __shfl_xor(mv, k, 64));
        if (d == 0)
            out_vw[(b * 4 + (v - 1)) * HW_ + p] = mv;

        #pragma unroll
        for (int g = 0; g < G_; ++g) simsum[g] = fmaf(sim[g], mv, simsum[g]);
        wsum += mv;
    }

    float wn = __builtin_amdgcn_rcpf(wsum + 1e-6f);
    #pragma unroll
    for (int g = 0; g < G_; ++g) s_sim[g][d][pxl] = simsum[g] * wn;
    __syncthreads();

    const int tx = tid & 31;
    const int ty = tid >> 5;
    float* so = out_sim + (size_t)b * G_ * DHW_ + ty * HW_ + h * W_ + w0 + tx;
    #pragma unroll
    for (int g = 0; g < G_; ++g) so[(size_t)g * DHW_] = s_sim[g][ty][tx];
}

// ---------------- conv3d 3x3x3, pad 1, d-blocked x4, ic-chunked x2 ----------------
__global__ __launch_bounds__(256) void k_conv1(
    const float* __restrict__ in,
    const float* __restrict__ wgt,
    const float* __restrict__ bias,
    float* __restrict__ out)
{
    __shared__ float in_s[4][6][10][34];
    __shared__ float w_t[216 * 8];
    const int tx = threadIdx.x, ty = threadIdx.y;
    const int tid = ty * 32 + tx;
    const int w0 = blockIdx.x * 32;
    const int h0 = blockIdx.y * 8;
    const int z  = blockIdx.z;
    const int b  = z >> 3;
    const int d0 = (z & 7) * 4;

    for (int i = tid; i < 1728; i += 256) {
        int oc = i / 216, tap = i - oc * 216;
        w_t[tap * 8 + oc] = wgt[i];
    }

    float acc[4][8];
    #pragma unroll
    for (int dd = 0; dd < 4; ++dd)
        #pragma unroll
        for (int oc = 0; oc < 8; ++oc) acc[dd][oc] = bias[oc];

    for (int ch = 0; ch < 2; ++ch) {
        if (ch) __syncthreads();
        for (int i = tid; i < 4 * 6 * 10 * 34; i += 256) {
            int wx = i % 34; int r = i / 34;
            int hy = r % 10; r /= 10;
            int dz = r % 6;  int icl = r / 6;
            int ic = ch * 4 + icl;
            int gw = w0 + wx - 1, gh = h0 + hy - 1, gd = d0 + dz - 1;
            float val = 0.f;
            if (gw >= 0 && gw < W_ && gh >= 0 && gh < H_ && gd >= 0 && gd < D_)
                val = in[((b * 8 + ic) * D_ + gd) * HW_ + gh * W_ + gw];
            in_s[icl][dz][hy][wx] = val;
        }
        __syncthreads();

        #pragma unroll 1
        for (int icdz = 0; icdz < 12; ++icdz) {
            int icl = icdz / 3, dz = icdz - 3 * (icdz / 3);
            #pragma unroll
            for (int hy = 0; hy < 3; ++hy)
                #pragma unroll
                for (int wx = 0; wx < 3; ++wx) {
                    int tap = (ch * 12 + icdz) * 9 + hy * 3 + wx;
                    float4 wa = *(const float4*)&w_t[tap * 8];
                    float4 wb = *(const float4*)&w_t[tap * 8 + 4];
                    #pragma unroll
                    for (int dd = 0; dd < 4; ++dd) {
                        float vv = in_s[icl][dz + dd][ty + hy][tx + wx];
                        acc[dd][0] = fmaf(vv, wa.x, acc[dd][0]);
                        acc[dd][1] = fmaf(vv, wa.y, acc[dd][1]);
                        acc[dd][2] = fmaf(vv, wa.z, acc[dd][2]);
                        acc[dd][3] = fmaf(vv, wa.w, acc[dd][3]);
                        acc[dd][4] = fmaf(vv, wb.x, acc[dd][4]);
                        acc[dd][5] = fmaf(vv, wb.y, acc[dd][5]);
                        acc[dd][6] = fmaf(vv, wb.z, acc[dd][6]);
                        acc[dd][7] = fmaf(vv, wb.w, acc[dd][7]);
                    }
                }
        }
    }

    #pragma unroll
    for (int dd = 0; dd < 4; ++dd)
        #pragma unroll
        for (int oc = 0; oc < 8; ++oc)
            out[((b * 8 + oc) * D_ + d0 + dd) * HW_ + (h0 + ty) * W_ + (w0 + tx)] =
                fmaxf(acc[dd][oc], 0.f);
}

__global__ __launch_bounds__(256) void k_conv2(
    const float* __restrict__ in,
    const float* __restrict__ wgt,
    const float* __restrict__ bias,
    float* __restrict__ out)
{
    __shared__ float in_s[4][6][10][34];
    __shared__ float w_s[216];
    const int tx = threadIdx.x, ty = threadIdx.y;
    const int tid = ty * 32 + tx;
    const int w0 = blockIdx.x * 32;
    const int h0 = blockIdx.y * 8;
    const int z  = blockIdx.z;
    const int b  = z >> 3;
    const int d0 = (z & 7) * 4;

    if (tid < 216) w_s[tid] = wgt[tid];

    float acc[4];
    #pragma unroll
    for (int dd = 0; dd < 4; ++dd) acc[dd] = bias[0];

    for (int ch = 0; ch < 2; ++ch) {
        if (ch) __syncthreads();
        for (int i = tid; i < 4 * 6 * 10 * 34; i += 256) {
            int wx = i % 34; int r = i / 34;
            int hy = r % 10; r /= 10;
            int dz = r % 6;  int icl = r / 6;
            int ic = ch * 4 + icl;
            int gw = w0 + wx - 1, gh = h0 + hy - 1, gd = d0 + dz - 1;
            float val = 0.f;
            if (gw >= 0 && gw < W_ && gh >= 0 && gh < H_ && gd >= 0 && gd < D_)
                val = in[((b * 8 + ic) * D_ + gd) * HW_ + gh * W_ + gw];
            in_s[icl][dz][hy][wx] = val;
        }
        __syncthreads();

        #pragma unroll 1
        for (int icdz = 0; icdz < 12; ++icdz) {
            int icl = icdz / 3, dz = icdz - 3 * (icdz / 3);
            #pragma unroll
            for (int hy = 0; hy < 3; ++hy)
                #pragma unroll
                for (int wx = 0; wx < 3; ++wx) {
                    float wv = w_s[(ch * 12 + icdz) * 9 + hy * 3 + wx];
                    #pragma unroll
                    for (int dd = 0; dd < 4; ++dd)
                        acc[dd] = fmaf(in_s[icl][dz + dd][ty + hy][tx + wx], wv, acc[dd]);
                }
        }
    }

    #pragma unroll
    for (int dd = 0; dd < 4; ++dd)
        out[(b * D_ + d0 + dd) * HW_ + (h0 + ty) * W_ + (w0 + tx)] = acc[dd];
}

// ---------------- final ----------------
__global__ __launch_bounds__(256) void k_final(
    const float* __restrict__ pvp,
    const float* __restrict__ depthv,
    float* __restrict__ out_depth,
    float* __restrict__ out_conf)
{
    int i = blockIdx.x * 256 + threadIdx.x;
    if (i >= B_ * HW_) return;
    int b = i / HW_;
    int p = i - b * HW_;

    const float* pp = pvp + b * DHW_ + p;
    const float* dv = depthv + b * DHW_ + p;

    float x[D_];
    float m = -3.4e38f;
    #pragma unroll
    for (int d = 0; d < D_; ++d) { x[d] = pp[d * HW_]; m = fmaxf(m, x[d]); }
    float s = 0.f;
    #pragma unroll
    for (int d = 0; d < D_; ++d) { x[d] = exp2f((x[d] - m) * LOG2E_); s += x[d]; }
    float inv = 1.f / s;

    float dep = 0.f, fd = 0.f;
    #pragma unroll
    for (int d = 0; d < D_; ++d) {
        float pv = x[d] * inv;
        x[d] = pv;
        dep = fmaf(pv, dv[d * HW_], dep);
        fd  = fmaf(pv, (float)d, fd);
    }
    int di = (int)fd;
    di = di < 0 ? 0 : (di > D_ - 1 ? D_ - 1 : di);
    float conf = 0.f;
    #pragma unroll
    for (int k = 0; k < 4; ++k) {
        int idx = di - 1 + k;
        if (idx >= 0 && idx < D_) conf += x[idx];
    }
    out_depth[i] = dep;
    out_conf[i]  = conf;
}

// ---------------- launch ----------------
extern "C" void kernel_launch(void* const* d_in, const int* in_sizes, int n_in,
                              void* d_out, int out_size, void* d_ws, size_t ws_size,
                              hipStream_t stream) {
    const float* feat   = (const float*)d_in[0];
    const float* pm     = (const float*)d_in[1];
    const float* depthv = (const float*)d_in[2];
    const float* reg_w1 = (const float*)d_in[3];
    const float* reg_b1 = (const float*)d_in[4];
    const float* reg_w2 = (const float*)d_in[5];
    const float* reg_b2 = (const float*)d_in[6];
    const float* pw_w1  = (const float*)d_in[7];
    const float* pw_b1  = (const float*)d_in[8];
    const float* pw_w2  = (const float*)d_in[9];
    const float* pw_b2  = (const float*)d_in[10];
    const float* pw_w3  = (const float*)d_in[11];
    const float* pw_b3  = (const float*)d_in[12];

    float* out = (float*)d_out;
    float* out_depth = out;
    float* out_conf  = out + B_*HW_;
    float* out_vw    = out + 2*B_*HW_;
    float* out_pvp   = out_vw + B_*4*HW_;
    float* out_sim   = out_pvp + B_*DHW_;

    float* ws      = (float*)d_ws;
    float* proj_ws = ws;                       // 96
    float* tabw    = ws + 128;                 // 1024
    _Float16* featT = (_Float16*)(ws + 2048);  // VB*HW*32 halves = 13.1 MB
    float* hid     = ws + 2048;                // fp32 41.9 MB, reuses featT region after k_main

    hipLaunchKernelGGL(k_proj, dim3(1), dim3(1024), 0, stream,
                       pm, pw_w1, pw_b1, pw_w2, pw_b2, pw_w3, pw_b3, proj_ws, tabw);

    hipLaunchKernelGGL(k_transpose, dim3(HW_/32, V_*B_), dim3(32, 32), 0, stream,
                       feat, featT);

    hipLaunchKernelGGL(k_main, dim3(W_/32, H_, B_), dim3(1024), 0, stream,
                       featT, depthv, proj_ws, tabw, out_vw, out_sim);

    hipLaunchKernelGGL(k_conv1, dim3(W_/32, H_/8, B_*D_/4), dim3(32, 8), 0, stream,
                       out_sim, reg_w1, reg_b1, hid);

    hipLaunchKernelGGL(k_conv2, dim3(W_/32, H_/8, B_*D_/4), dim3(32, 8), 0, stream,
                       hid, reg_w2, reg_b2, out_pvp);

    hipLaunchKernelGGL(k_final, dim3((B_*HW_ + 255)/256), dim3(256), 0, stream,
                       out_pvp, depthv, out_depth, out_conf);
}

// Round 5
// 243.624 us; speedup vs baseline: 2.9237x; 1.3918x over previous
//
#include <hip/hip_runtime.h>
#include <hip/hip_bf16.h>
#include <hip/hip_fp16.h>

#define V_  5
#define B_  2
#define C_  32
#define H_  128
#define W_  160
#define D_  32
#define G_  8
#define HW_  (H_*W_)
#define DHW_ (D_*HW_)

#define LOG2E_ 1.4426950408889634f
#define LN2_   0.6931471805599453f
#define LN8_   2.0794415416798357f

typedef _Float16 h8 __attribute__((ext_vector_type(8)));
typedef _Float16 h4 __attribute__((ext_vector_type(4)));
typedef float    f4 __attribute__((ext_vector_type(4)));

// ws layout (floats):
//  [0..95]    proj
//  [128..1151] mlp sigmoid table
//  [2048 ..]  region A: featT fp16 (13.1MB) — dead after k_main; hidh fp16 (21MB) overwrites it
//  [2048+5242880 ..] simh fp16 (21MB) — written by k_main, read by conv1

// ---------------- projection + MLP table setup ----------------

__device__ inline void combine_mat(const float* m, float out[4][4]) {
    const float* ext = m;
    const float* K   = m + 16;
    for (int r = 0; r < 4; ++r)
        for (int c = 0; c < 4; ++c)
            out[r][c] = ext[r*4 + c];
    for (int r = 0; r < 3; ++r)
        for (int c = 0; c < 4; ++c) {
            float s = 0.f;
            for (int k = 0; k < 3; ++k) s += K[r*4 + k] * ext[k*4 + c];
            out[r][c] = s;
        }
}

__device__ inline void invert4(const float Ain[4][4], float Inv[4][4]) {
    float A[4][4];
    for (int r = 0; r < 4; ++r)
        for (int c = 0; c < 4; ++c) {
            A[r][c]   = Ain[r][c];
            Inv[r][c] = (r == c) ? 1.f : 0.f;
        }
    for (int k = 0; k < 4; ++k) {
        int p = k; float best = fabsf(A[k][k]);
        for (int r = k + 1; r < 4; ++r) {
            float v = fabsf(A[r][k]);
            if (v > best) { best = v; p = r; }
        }
        if (p != k) {
            for (int j = 0; j < 4; ++j) {
                float t = A[k][j]; A[k][j] = A[p][j]; A[p][j] = t;
                t = Inv[k][j]; Inv[k][j] = Inv[p][j]; Inv[p][j] = t;
            }
        }
        float dinv = 1.f / A[k][k];
        for (int j = 0; j < 4; ++j) { A[k][j] *= dinv; Inv[k][j] *= dinv; }
        for (int r = 0; r < 4; ++r) {
            if (r == k) continue;
            float f = A[r][k];
            for (int j = 0; j < 4; ++j) {
                A[r][j]  -= f * A[k][j];
                Inv[r][j] -= f * Inv[k][j];
            }
        }
    }
}

__global__ __launch_bounds__(1024) void k_proj(
    const float* __restrict__ pm,
    const float* __restrict__ pw_w1, const float* __restrict__ pw_b1,
    const float* __restrict__ pw_w2, const float* __restrict__ pw_b2,
    const float* __restrict__ pw_w3, const float* __restrict__ pw_b3,
    float* __restrict__ proj_ws, float* __restrict__ tabw)
{
    int tid = threadIdx.x;
    if (tid < B_) {
        int b = tid;
        float C0[4][4], C0inv[4][4];
        combine_mat(pm + (b * V_ + 0) * 32, C0);
        invert4(C0, C0inv);
        for (int v = 1; v < V_; ++v) {
            float Cv[4][4];
            combine_mat(pm + (b * V_ + v) * 32, Cv);
            float* o = proj_ws + (b * 4 + (v - 1)) * 12;
            for (int r = 0; r < 3; ++r)
                for (int c = 0; c < 4; ++c) {
                    float s = 0.f;
                    for (int k = 0; k < 4; ++k) s += Cv[r][k] * C0inv[k][c];
                    o[r*4 + c] = s;
                }
        }
    }
    float ent = (float)tid * (LN8_ / 1023.0f);
    float h2[8];
    #pragma unroll
    for (int j = 0; j < 8; ++j) h2[j] = pw_b2[j];
    for (int k = 0; k < 16; ++k) {
        float h1 = fmaxf(ent * pw_w1[k] + pw_b1[k], 0.f);
        #pragma unroll
        for (int j = 0; j < 8; ++j) h2[j] += pw_w2[j*16 + k] * h1;
    }
    float o3 = pw_b3[0];
    #pragma unroll
    for (int j = 0; j < 8; ++j) o3 += pw_w3[j] * fmaxf(h2[j], 0.f);
    tabw[tid] = 1.f / (1.f + expf(-o3));
}

// ---------------- feature transpose: [V][B][C][H][W] f32 -> [VB][HW][C] fp16 ----------------
__global__ __launch_bounds__(1024) void k_transpose(
    const float* __restrict__ in, _Float16* __restrict__ out)
{
    __shared__ float s[32][33];
    const int tx = threadIdx.x, ty = threadIdx.y;
    const int hw0 = blockIdx.x * 32;
    const int vb  = blockIdx.y;
    s[ty][tx] = in[(vb * 32 + ty) * HW_ + hw0 + tx];
    __syncthreads();
    out[((size_t)vb * HW_ + hw0 + ty) * 32 + tx] = (_Float16)s[tx][ty];
}

// ---------------- main fused kernel ----------------
__global__ __launch_bounds__(1024) void k_main(
    const _Float16* __restrict__ featT, // [VB][HW][32] fp16
    const float* __restrict__ depthv,   // [B][D][H][W]
    const float* __restrict__ proj_ws,
    const float* __restrict__ tabw,
    float* __restrict__ out_vw,         // [B][4][H][W]
    float* __restrict__ out_sim,        // [B][G][D][H][W] fp32 (canonical output)
    _Float16* __restrict__ simh)        // [B][D][H][W][8] fp16 (conv1 feed)
{
    const int tid = threadIdx.x;
    const int wv   = tid >> 6;
    const int lane = tid & 63;
    const int j    = lane >> 5;
    const int d    = lane & 31;
    const int pxl  = wv * 2 + j;
    const int w0 = blockIdx.x * 32;
    const int h  = blockIdx.y;
    const int b  = blockIdx.z;
    const int w  = w0 + pxl;
    const int p  = h * W_ + w;

    __shared__ float tab_s[1024];
    __shared__ float proj_s[48];
    __shared__ float s_sim[G_][32][33];

    tab_s[tid] = tabw[tid];
    if (tid < 48) proj_s[tid] = proj_ws[b * 48 + tid];
    __syncthreads();

    const h8* rp = (const h8*)(featT + ((size_t)b * HW_ + p) * 32);
    float refc[32];
    #pragma unroll
    for (int cc = 0; cc < 4; ++cc) {
        h8 rv = rp[cc];
        #pragma unroll
        for (int k = 0; k < 8; ++k) refc[cc * 8 + k] = (float)rv[k];
    }

    const float depth = depthv[(b * D_ + d) * HW_ + p];
    const float xf = (float)w, yf = (float)h;

    float simsum[G_];
    #pragma unroll
    for (int g = 0; g < G_; ++g) simsum[g] = 0.f;
    float wsum = 0.f;

    for (int v = 1; v < V_; ++v) {
        const float* P = &proj_s[(v - 1) * 12];
        float px = (P[0]*xf + P[1]*yf + P[2])  * depth + P[3];
        float py = (P[4]*xf + P[5]*yf + P[6])  * depth + P[7];
        float pz = (P[8]*xf + P[9]*yf + P[10]) * depth + P[11];
        float rz = __builtin_amdgcn_rcpf(pz);
        float xs = px * rz;
        float ys = py * rz;

        float xr = rintf(xs);
        float yr = rintf(ys);
        xs = (fabsf(xs - xr) < 1e-4f) ? xr : xs;
        ys = (fabsf(ys - yr) < 1e-4f) ? yr : ys;

        float x0 = floorf(xs), y0 = floorf(ys);
        float wx1 = xs - x0,  wy1 = ys - y0;
        float wx0 = 1.f - wx1, wy0 = 1.f - wy1;

        bool vx0 = (x0 >= 0.f)     && (x0 <= (float)(W_-1));
        bool vx1 = (x0+1.f >= 0.f) && (x0+1.f <= (float)(W_-1));
        bool vy0 = (y0 >= 0.f)     && (y0 <= (float)(H_-1));
        bool vy1 = (y0+1.f >= 0.f) && (y0+1.f <= (float)(H_-1));

        int xc0 = (int)fminf(fmaxf(x0,     0.f), (float)(W_-1));
        int xc1 = (int)fminf(fmaxf(x0+1.f, 0.f), (float)(W_-1));
        int yc0 = (int)fminf(fmaxf(y0,     0.f), (float)(H_-1));
        int yc1 = (int)fminf(fmaxf(y0+1.f, 0.f), (float)(H_-1));

        float w00 = (vx0 && vy0) ? (wx0 * wy0) : 0.f;
        float w01 = (vx1 && vy0) ? (wx1 * wy0) : 0.f;
        float w10 = (vx0 && vy1) ? (wx0 * wy1) : 0.f;
        float w11 = (vx1 && vy1) ? (wx1 * wy1) : 0.f;

        const _Float16* vbp = featT + (size_t)(v * B_ + b) * HW_ * 32;

        float sim[G_];
        #pragma unroll
        for (int g = 0; g < G_; ++g) sim[g] = 0.f;

        bool top = __any(w00 > 0.f || w01 > 0.f);
        bool bot = __any(w10 > 0.f || w11 > 0.f);

        if (top) {
            const h8* t00 = (const h8*)(vbp + (size_t)(yc0 * W_ + xc0) * 32);
            const h8* t01 = (const h8*)(vbp + (size_t)(yc0 * W_ + xc1) * 32);
            #pragma unroll
            for (int cc = 0; cc < 4; ++cc) {
                h8 a = t00[cc], bb = t01[cc];
                #pragma unroll
                for (int k = 0; k < 8; ++k) {
                    float fv = fmaf((float)bb[k], w01, (float)a[k] * w00);
                    int g = cc * 2 + (k >> 2);
                    sim[g] = fmaf(fv, refc[cc * 8 + k], sim[g]);
                }
            }
        }
        if (bot) {
            const h8* t10 = (const h8*)(vbp + (size_t)(yc1 * W_ + xc0) * 32);
            const h8* t11 = (const h8*)(vbp + (size_t)(yc1 * W_ + xc1) * 32);
            #pragma unroll
            for (int cc = 0; cc < 4; ++cc) {
                h8 cq = t10[cc], dq = t11[cc];
                #pragma unroll
                for (int k = 0; k < 8; ++k) {
                    float fv = fmaf((float)dq[k], w11, (float)cq[k] * w10);
                    int g = cc * 2 + (k >> 2);
                    sim[g] = fmaf(fv, refc[cc * 8 + k], sim[g]);
                }
            }
        }

        #pragma unroll
        for (int g = 0; g < G_; ++g) sim[g] *= 0.25f;

        float m = sim[0];
        #pragma unroll
        for (int g = 1; g < G_; ++g) m = fmaxf(m, sim[g]);
        float es = 0.f, edot = 0.f;
        #pragma unroll
        for (int g = 0; g < G_; ++g) {
            float e = exp2f((sim[g] - m) * LOG2E_);
            es += e;
            edot = fmaf(e, sim[g], edot);
        }
        float inv_es = __builtin_amdgcn_rcpf(es);
        float ent = m + log2f(es) * LN2_ - edot * inv_es;

        float t = ent * (1023.0f / LN8_);
        t = fminf(fmaxf(t, 0.f), 1022.999f);
        int it = (int)t;
        float fr = t - (float)it;
        float lo = tab_s[it], hi = tab_s[it + 1];
        float sig = fmaf(hi - lo, fr, lo);

        float mv = sig;
        #pragma unroll
        for (int k = 16; k >= 1; k >>= 1)
            mv = fmaxf(mv, __shfl_xor(mv, k, 64));
        if (d == 0)
            out_vw[(b * 4 + (v - 1)) * HW_ + p] = mv;

        #pragma unroll
        for (int g = 0; g < G_; ++g) simsum[g] = fmaf(sim[g], mv, simsum[g]);
        wsum += mv;
    }

    float wn = __builtin_amdgcn_rcpf(wsum + 1e-6f);
    #pragma unroll
    for (int g = 0; g < G_; ++g) s_sim[g][d][pxl] = simsum[g] * wn;
    __syncthreads();

    const int tx = tid & 31;
    const int ty = tid >> 5;
    float* so = out_sim + (size_t)b * G_ * DHW_ + ty * HW_ + h * W_ + w0 + tx;
    h8 hv;
    #pragma unroll
    for (int g = 0; g < G_; ++g) {
        float val = s_sim[g][ty][tx];
        so[(size_t)g * DHW_] = val;
        hv[g] = (_Float16)val;
    }
    *(h8*)(simh + ((size_t)(b * D_ + ty) * HW_ + h * W_ + w0 + tx) * 8) = hv;
}

// ---------------- conv3d via MFMA implicit GEMM ----------------
// K = 28 taps x 8 ic (tap-major, k = tap*8+ic), M = 16 (oc padded), N = 16 voxels/tile.
// Layouts (HW-verified): A[m=lane&15][k=quad*8+j], B[k=quad*8+j][n=lane&15],
// C/D: col=lane&15, row=quad*4+reg.
// grid (W/32, H/8, B*D), block 256 (4 waves, 4 tiles each -> 8h x 32w outputs).

__global__ __launch_bounds__(256) void k_conv1m(
    const _Float16* __restrict__ in,   // [B][D][H][W][8] fp16
    const float* __restrict__ wgt,     // [8][8][27] fp32
    const float* __restrict__ bias,    // [8]
    _Float16* __restrict__ outh)       // [B][D][H][W][8] fp16
{
    __shared__ _Float16 halo[3*10*34*8];   // 16320 B
    __shared__ _Float16 wlds[28*16*8];     // 7168 B, [tap][m][ic]
    const int tid = threadIdx.x;
    const int w0 = blockIdx.x * 32;
    const int h0 = blockIdx.y * 8;
    const int z  = blockIdx.z;
    const int b  = z >> 5;
    const int dd = z & 31;

    for (int i = tid; i < 28*16*8; i += 256) {
        int ic = i & 7; int m = (i >> 3) & 15; int tap = i >> 7;
        float v = (tap < 27 && m < 8) ? wgt[(m*8 + ic)*27 + tap] : 0.f;
        wlds[i] = (_Float16)v;
    }
    for (int pos = tid; pos < 1020; pos += 256) {
        int wx = pos % 34; int r = pos / 34; int hy = r % 10; int dz = r / 10;
        int gw = w0 + wx - 1, gh = h0 + hy - 1, gd = dd + dz - 1;
        uint4 val = make_uint4(0u, 0u, 0u, 0u);
        if (gw >= 0 && gw < W_ && gh >= 0 && gh < H_ && gd >= 0 && gd < D_)
            val = *(const uint4*)(in + (((size_t)(b*D_ + gd)*H_ + gh)*W_ + gw)*8);
        *(uint4*)(halo + pos*8) = val;
    }
    __syncthreads();

    const int wave = tid >> 6, lane = tid & 63;
    const int n = lane & 15, quad = lane >> 4;

    h8 afrag[7];
    int chunkoff[7];
    #pragma unroll
    for (int c = 0; c < 7; ++c) {
        int tap = c*4 + quad;
        afrag[c] = *(const h8*)(wlds + (tap*16 + n)*8);
        int tapc = tap > 26 ? 26 : tap;
        int dz = tapc / 9; int rem = tapc - dz*9;
        int hyo = rem / 3; int wxo = rem - hyo*3;
        chunkoff[c] = ((dz*10 + hyo)*34 + wxo)*8;
    }
    f4 binit;
    #pragma unroll
    for (int reg = 0; reg < 4; ++reg)
        binit[reg] = (quad < 2) ? bias[quad*4 + reg] : 0.f;

    #pragma unroll
    for (int it = 0; it < 4; ++it) {
        int t = wave*4 + it;
        int h_row = t >> 1, whalf = t & 1;
        int tileoff = (h_row*34 + whalf*16 + n)*8;
        f4 acc = binit;
        #pragma unroll
        for (int c = 0; c < 7; ++c) {
            h8 bfrag = *(const h8*)(halo + chunkoff[c] + tileoff);
            acc = __builtin_amdgcn_mfma_f32_16x16x32_f16(afrag[c], bfrag, acc, 0, 0, 0);
        }
        if (quad < 2) {
            h4 hv;
            #pragma unroll
            for (int reg = 0; reg < 4; ++reg) hv[reg] = (_Float16)fmaxf(acc[reg], 0.f);
            *(h4*)(outh + (((size_t)(b*D_ + dd)*H_ + h0 + h_row)*W_ + w0 + whalf*16 + n)*8 + quad*4) = hv;
        }
    }
}

__global__ __launch_bounds__(256) void k_conv2m(
    const _Float16* __restrict__ in,   // [B][D][H][W][8] fp16
    const float* __restrict__ wgt,     // [1][8][27] fp32
    const float* __restrict__ bias,    // [1]
    float* __restrict__ out)           // [B][D][H][W] fp32
{
    __shared__ _Float16 halo[3*10*34*8];
    __shared__ _Float16 wlds[28*16*8];
    const int tid = threadIdx.x;
    const int w0 = blockIdx.x * 32;
    const int h0 = blockIdx.y * 8;
    const int z  = blockIdx.z;
    const int b  = z >> 5;
    const int dd = z & 31;

    for (int i = tid; i < 28*16*8; i += 256) {
        int ic = i & 7; int m = (i >> 3) & 15; int tap = i >> 7;
        float v = (tap < 27 && m == 0) ? wgt[ic*27 + tap] : 0.f;
        wlds[i] = (_Float16)v;
    }
    for (int pos = tid; pos < 1020; pos += 256) {
        int wx = pos % 34; int r = pos / 34; int hy = r % 10; int dz = r / 10;
        int gw = w0 + wx - 1, gh = h0 + hy - 1, gd = dd + dz - 1;
        uint4 val = make_uint4(0u, 0u, 0u, 0u);
        if (gw >= 0 && gw < W_ && gh >= 0 && gh < H_ && gd >= 0 && gd < D_)
            val = *(const uint4*)(in + (((size_t)(b*D_ + gd)*H_ + gh)*W_ + gw)*8);
        *(uint4*)(halo + pos*8) = val;
    }
    __syncthreads();

    const int wave = tid >> 6, lane = tid & 63;
    const int n = lane & 15, quad = lane >> 4;

    h8 afrag[7];
    int chunkoff[7];
    #pragma unroll
    for (int c = 0; c < 7; ++c) {
        int tap = c*4 + quad;
        afrag[c] = *(const h8*)(wlds + (tap*16 + n)*8);
        int tapc = tap > 26 ? 26 : tap;
        int dz = tapc / 9; int rem = tapc - dz*9;
        int hyo = rem / 3; int wxo = rem - hyo*3;
        chunkoff[c] = ((dz*10 + hyo)*34 + wxo)*8;
    }
    const float b0 = bias[0];

    #pragma unroll
    for (int it = 0; it < 4; ++it) {
        int t = wave*4 + it;
        int h_row = t >> 1, whalf = t & 1;
        int tileoff = (h_row*34 + whalf*16 + n)*8;
        f4 acc;
        acc[0] = (quad == 0) ? b0 : 0.f;
        acc[1] = 0.f; acc[2] = 0.f; acc[3] = 0.f;
        #pragma unroll
        for (int c = 0; c < 7; ++c) {
            h8 bfrag = *(const h8*)(halo + chunkoff[c] + tileoff);
            acc = __builtin_amdgcn_mfma_f32_16x16x32_f16(afrag[c], bfrag, acc, 0, 0, 0);
        }
        if (quad == 0)
            out[(((size_t)(b*D_ + dd)*H_ + h0 + h_row)*W_ + w0 + whalf*16 + n)] = acc[0];
    }
}

// ---------------- final: softmax over D, depth, confidence ----------------
__global__ __launch_bounds__(256) void k_final(
    const float* __restrict__ pvp,
    const float* __restrict__ depthv,
    float* __restrict__ out_depth,
    float* __restrict__ out_conf)
{
    int i = blockIdx.x * 256 + threadIdx.x;
    if (i >= B_ * HW_) return;
    int b = i / HW_;
    int p = i - b * HW_;

    const float* pp = pvp + b * DHW_ + p;
    const float* dv = depthv + b * DHW_ + p;

    float x[D_];
    float m = -3.4e38f;
    #pragma unroll
    for (int d = 0; d < D_; ++d) { x[d] = pp[d * HW_]; m = fmaxf(m, x[d]); }
    float s = 0.f;
    #pragma unroll
    for (int d = 0; d < D_; ++d) { x[d] = exp2f((x[d] - m) * LOG2E_); s += x[d]; }
    float inv = 1.f / s;

    float dep = 0.f, fd = 0.f;
    #pragma unroll
    for (int d = 0; d < D_; ++d) {
        float pv = x[d] * inv;
        x[d] = pv;
        dep = fmaf(pv, dv[d * HW_], dep);
        fd  = fmaf(pv, (float)d, fd);
    }
    int di = (int)fd;
    di = di < 0 ? 0 : (di > D_ - 1 ? D_ - 1 : di);
    float conf = 0.f;
    #pragma unroll
    for (int k = 0; k < 4; ++k) {
        int idx = di - 1 + k;
        if (idx >= 0 && idx < D_) conf += x[idx];
    }
    out_depth[i] = dep;
    out_conf[i]  = conf;
}

// ---------------- launch ----------------
extern "C" void kernel_launch(void* const* d_in, const int* in_sizes, int n_in,
                              void* d_out, int out_size, void* d_ws, size_t ws_size,
                              hipStream_t stream) {
    const float* feat   = (const float*)d_in[0];
    const float* pm     = (const float*)d_in[1];
    const float* depthv = (const float*)d_in[2];
    const float* reg_w1 = (const float*)d_in[3];
    const float* reg_b1 = (const float*)d_in[4];
    const float* reg_w2 = (const float*)d_in[5];
    const float* reg_b2 = (const float*)d_in[6];
    const float* pw_w1  = (const float*)d_in[7];
    const float* pw_b1  = (const float*)d_in[8];
    const float* pw_w2  = (const float*)d_in[9];
    const float* pw_b2  = (const float*)d_in[10];
    const float* pw_w3  = (const float*)d_in[11];
    const float* pw_b3  = (const float*)d_in[12];

    float* out = (float*)d_out;
    float* out_depth = out;
    float* out_conf  = out + B_*HW_;
    float* out_vw    = out + 2*B_*HW_;
    float* out_pvp   = out_vw + B_*4*HW_;
    float* out_sim   = out_pvp + B_*DHW_;

    float* ws      = (float*)d_ws;
    float* proj_ws = ws;                        // 96 floats
    float* tabw    = ws + 128;                  // 1024 floats
    _Float16* featT = (_Float16*)(ws + 2048);   // 6.55M halves (13.1 MB), dead after k_main
    _Float16* hidh  = (_Float16*)(ws + 2048);   // 10.49M halves (21 MB), overwrites featT
    _Float16* simh  = (_Float16*)(ws + 2048 + 5242880); // 10.49M halves (21 MB)

    hipLaunchKernelGGL(k_proj, dim3(1), dim3(1024), 0, stream,
                       pm, pw_w1, pw_b1, pw_w2, pw_b2, pw_w3, pw_b3, proj_ws, tabw);

    hipLaunchKernelGGL(k_transpose, dim3(HW_/32, V_*B_), dim3(32, 32), 0, stream,
                       feat, featT);

    hipLaunchKernelGGL(k_main, dim3(W_/32, H_, B_), dim3(1024), 0, stream,
                       featT, depthv, proj_ws, tabw, out_vw, out_sim, simh);

    hipLaunchKernelGGL(k_conv1m, dim3(W_/32, H_/8, B_*D_), dim3(256), 0, stream,
                       simh, reg_w1, reg_b1, hidh);

    hipLaunchKernelGGL(k_conv2m, dim3(W_/32, H_/8, B_*D_), dim3(256), 0, stream,
                       hidh, reg_w2, reg_b2, out_pvp);

    hipLaunchKernelGGL(k_final, dim3((B_*HW_ + 255)/256), dim3(256), 0, stream,
                       out_pvp, depthv, out_depth, out_conf);
}

// Round 7
// 213.207 us; speedup vs baseline: 3.3409x; 1.1427x over previous
//
#include <hip/hip_runtime.h>
#include <hip/hip_bf16.h>
#include <hip/hip_fp16.h>

#define V_  5
#define B_  2
#define C_  32
#define H_  128
#define W_  160
#define D_  32
#define G_  8
#define HW_  (H_*W_)
#define DHW_ (D_*HW_)

#define LOG2E_ 1.4426950408889634f
#define LN2_   0.6931471805599453f
#define LN8_   2.0794415416798357f

typedef _Float16 h8 __attribute__((ext_vector_type(8)));
typedef _Float16 h4 __attribute__((ext_vector_type(4)));
typedef _Float16 h2 __attribute__((ext_vector_type(2)));
typedef float    f4 __attribute__((ext_vector_type(4)));

__device__ inline float fdot2f(h2 a, h2 b, float c) {
#if __has_builtin(__builtin_amdgcn_fdot2)
    return __builtin_amdgcn_fdot2(a, b, c, false);
#else
    return fmaf((float)a[0], (float)b[0], fmaf((float)a[1], (float)b[1], c));
#endif
}

// ws layout (floats):
//  [0..95]      proj
//  [128..1151]  mlp sigmoid table
//  [1152..2943] wh1 fp16 [28][16][8]
//  [2944..4735] wh2 fp16 [28][16][8]
//  [4736 ..]    featT fp16 (13.1MB, dead after k_main) / hidh fp16 (21MB)
//  [4736+5242880 ..] simh fp16 (21MB)

// ---------------- projection + MLP table + conv-weight packing ----------------

__device__ inline void combine_mat(const float* m, float out[4][4]) {
    const float* ext = m;
    const float* K   = m + 16;
    for (int r = 0; r < 4; ++r)
        for (int c = 0; c < 4; ++c)
            out[r][c] = ext[r*4 + c];
    for (int r = 0; r < 3; ++r)
        for (int c = 0; c < 4; ++c) {
            float s = 0.f;
            for (int k = 0; k < 3; ++k) s += K[r*4 + k] * ext[k*4 + c];
            out[r][c] = s;
        }
}

__device__ inline void invert4(const float Ain[4][4], float Inv[4][4]) {
    float A[4][4];
    for (int r = 0; r < 4; ++r)
        for (int c = 0; c < 4; ++c) {
            A[r][c]   = Ain[r][c];
            Inv[r][c] = (r == c) ? 1.f : 0.f;
        }
    for (int k = 0; k < 4; ++k) {
        int p = k; float best = fabsf(A[k][k]);
        for (int r = k + 1; r < 4; ++r) {
            float v = fabsf(A[r][k]);
            if (v > best) { best = v; p = r; }
        }
        if (p != k) {
            for (int j = 0; j < 4; ++j) {
                float t = A[k][j]; A[k][j] = A[p][j]; A[p][j] = t;
                t = Inv[k][j]; Inv[k][j] = Inv[p][j]; Inv[p][j] = t;
            }
        }
        float dinv = 1.f / A[k][k];
        for (int j = 0; j < 4; ++j) { A[k][j] *= dinv; Inv[k][j] *= dinv; }
        for (int r = 0; r < 4; ++r) {
            if (r == k) continue;
            float f = A[r][k];
            for (int j = 0; j < 4; ++j) {
                A[r][j]  -= f * A[k][j];
                Inv[r][j] -= f * Inv[k][j];
            }
        }
    }
}

__global__ __launch_bounds__(1024) void k_proj(
    const float* __restrict__ pm,
    const float* __restrict__ pw_w1, const float* __restrict__ pw_b1,
    const float* __restrict__ pw_w2, const float* __restrict__ pw_b2,
    const float* __restrict__ pw_w3, const float* __restrict__ pw_b3,
    const float* __restrict__ reg_w1, const float* __restrict__ reg_w2,
    float* __restrict__ proj_ws, float* __restrict__ tabw,
    _Float16* __restrict__ wh1, _Float16* __restrict__ wh2)
{
    int tid = threadIdx.x;
    if (tid < B_) {
        int b = tid;
        float C0[4][4], C0inv[4][4];
        combine_mat(pm + (b * V_ + 0) * 32, C0);
        invert4(C0, C0inv);
        for (int v = 1; v < V_; ++v) {
            float Cv[4][4];
            combine_mat(pm + (b * V_ + v) * 32, Cv);
            float* o = proj_ws + (b * 4 + (v - 1)) * 12;
            for (int r = 0; r < 3; ++r)
                for (int c = 0; c < 4; ++c) {
                    float s = 0.f;
                    for (int k = 0; k < 4; ++k) s += Cv[r][k] * C0inv[k][c];
                    o[r*4 + c] = s;
                }
        }
    }
    // pack conv weights fp16 [tap(28)][m(16)][ic(8)]
    for (int i = tid; i < 28*16*8; i += 1024) {
        int ic = i & 7; int m = (i >> 3) & 15; int tap = i >> 7;
        wh1[i] = (_Float16)((tap < 27 && m < 8) ? reg_w1[(m*8 + ic)*27 + tap] : 0.f);
        wh2[i] = (_Float16)((tap < 27 && m == 0) ? reg_w2[ic*27 + tap] : 0.f);
    }
    // MLP sigmoid table over ent in [0, ln 8]
    float ent = (float)tid * (LN8_ / 1023.0f);
    float h2v[8];
    #pragma unroll
    for (int j = 0; j < 8; ++j) h2v[j] = pw_b2[j];
    for (int k = 0; k < 16; ++k) {
        float h1 = fmaxf(ent * pw_w1[k] + pw_b1[k], 0.f);
        #pragma unroll
        for (int j = 0; j < 8; ++j) h2v[j] += pw_w2[j*16 + k] * h1;
    }
    float o3 = pw_b3[0];
    #pragma unroll
    for (int j = 0; j < 8; ++j) o3 += pw_w3[j] * fmaxf(h2v[j], 0.f);
    tabw[tid] = 1.f / (1.f + expf(-o3));
}

// ---------------- feature transpose: [V][B][C][H][W] f32 -> [VB][HW][C] fp16 ----------------
__global__ __launch_bounds__(1024) void k_transpose(
    const float* __restrict__ in, _Float16* __restrict__ out)
{
    __shared__ float s[32][33];
    const int tx = threadIdx.x, ty = threadIdx.y;
    const int tid = ty * 32 + tx;
    const int hw0 = blockIdx.x * 32;
    const int vb  = blockIdx.y;
    s[ty][tx] = in[(vb * 32 + ty) * HW_ + hw0 + tx];
    __syncthreads();
    if (tid < 256) {
        int hw = tid >> 3, q = tid & 7;
        h4 hv;
        #pragma unroll
        for (int i = 0; i < 4; ++i) hv[i] = (_Float16)s[q*4 + i][hw];
        *(h4*)(out + ((size_t)vb * HW_ + hw0 + hw) * 32 + q*4) = hv;
    }
}

// ---------------- main fused kernel ----------------
// grid (W/32, H, B), block 1024. wave wv: pixels {2wv,2wv+1} x 32 depths; lane = j*32+d.
__global__ __launch_bounds__(1024) void k_main(
    const _Float16* __restrict__ featT, // [VB][HW][32] fp16
    const float* __restrict__ depthv,   // [B][D][H][W]
    const float* __restrict__ proj_ws,
    const float* __restrict__ tabw,
    float* __restrict__ out_vw,         // [B][4][H][W]
    float* __restrict__ out_sim,        // [B][G][D][H][W] fp32
    _Float16* __restrict__ simh)        // [B][D][H][W][8] fp16
{
    const int tid = threadIdx.x;
    const int wv   = tid >> 6;
    const int lane = tid & 63;
    const int j    = lane >> 5;
    const int d    = lane & 31;
    const int pxl  = wv * 2 + j;
    const int w0 = blockIdx.x * 32;
    const int h  = blockIdx.y;
    const int b  = blockIdx.z;
    const int w  = w0 + pxl;
    const int p  = h * W_ + w;

    __shared__ float tab_s[1024];
    __shared__ float proj_s[48];
    __shared__ float s_sim[G_][32][33];

    tab_s[tid] = tabw[tid];
    if (tid < 48) proj_s[tid] = proj_ws[b * 48 + tid];
    __syncthreads();

    // ref fragment (view 0): keep in fp16 registers as 16x h2
    const h8* rp = (const h8*)(featT + ((size_t)b * HW_ + p) * 32);
    h8 r8[4];
    #pragma unroll
    for (int cc = 0; cc < 4; ++cc) r8[cc] = rp[cc];

    const float depth = depthv[(b * D_ + d) * HW_ + p];
    const float xf = (float)w, yf = (float)h;

    float simsum[G_];
    #pragma unroll
    for (int g = 0; g < G_; ++g) simsum[g] = 0.f;
    float wsum = 0.f;

    for (int v = 1; v < V_; ++v) {
        const float* P = &proj_s[(v - 1) * 12];
        float px = (P[0]*xf + P[1]*yf + P[2])  * depth + P[3];
        float py = (P[4]*xf + P[5]*yf + P[6])  * depth + P[7];
        float pz = (P[8]*xf + P[9]*yf + P[10]) * depth + P[11];
        float rz = __builtin_amdgcn_rcpf(pz);
        float xs = px * rz;
        float ys = py * rz;

        // snap near-integer coords (<=1e-4 px shift; makes zero-weight rows exact)
        float xr = rintf(xs);
        float yr = rintf(ys);
        xs = (fabsf(xs - xr) < 1e-4f) ? xr : xs;
        ys = (fabsf(ys - yr) < 1e-4f) ? yr : ys;

        float x0 = floorf(xs), y0 = floorf(ys);
        float wx1 = xs - x0,  wy1 = ys - y0;
        float wx0 = 1.f - wx1, wy0 = 1.f - wy1;

        bool vx0 = (x0 >= 0.f)     && (x0 <= (float)(W_-1));
        bool vx1 = (x0+1.f >= 0.f) && (x0+1.f <= (float)(W_-1));
        bool vy0 = (y0 >= 0.f)     && (y0 <= (float)(H_-1));
        bool vy1 = (y0+1.f >= 0.f) && (y0+1.f <= (float)(H_-1));

        int xc0 = (int)fminf(fmaxf(x0,     0.f), (float)(W_-1));
        int xc1 = (int)fminf(fmaxf(x0+1.f, 0.f), (float)(W_-1));
        int yc0 = (int)fminf(fmaxf(y0,     0.f), (float)(H_-1));
        int yc1 = (int)fminf(fmaxf(y0+1.f, 0.f), (float)(H_-1));

        float w00 = (vx0 && vy0) ? (wx0 * wy0) : 0.f;
        float w01 = (vx1 && vy0) ? (wx1 * wy0) : 0.f;
        float w10 = (vx0 && vy1) ? (wx0 * wy1) : 0.f;
        float w11 = (vx1 && vy1) ? (wx1 * wy1) : 0.f;

        const _Float16* vbp = featT + (size_t)(v * B_ + b) * HW_ * 32;

        float sim[G_];
        #pragma unroll
        for (int g = 0; g < G_; ++g) sim[g] = 0.f;

        bool top = __any(w00 > 0.f || w01 > 0.f);
        bool bot = __any(w10 > 0.f || w11 > 0.f);

        if (top) {
            h2 w00h = { (_Float16)w00, (_Float16)w00 };
            h2 w01h = { (_Float16)w01, (_Float16)w01 };
            const h8* t00 = (const h8*)(vbp + (size_t)(yc0 * W_ + xc0) * 32);
            const h8* t01 = (const h8*)(vbp + (size_t)(yc0 * W_ + xc1) * 32);
            #pragma unroll
            for (int cc = 0; cc < 4; ++cc) {
                h8 a = t00[cc], bb = t01[cc];
                const h2* ap = (const h2*)&a;
                const h2* bp = (const h2*)&bb;
                const h2* rv2 = (const h2*)&r8[cc];
                #pragma unroll
                for (int jp = 0; jp < 4; ++jp) {
                    h2 fv = ap[jp] * w00h + bp[jp] * w01h;
                    int g = cc*2 + (jp >> 1);
                    sim[g] = fdot2f(fv, rv2[jp], sim[g]);
                }
            }
        }
        if (bot) {
            h2 w10h = { (_Float16)w10, (_Float16)w10 };
            h2 w11h = { (_Float16)w11, (_Float16)w11 };
            const h8* t10 = (const h8*)(vbp + (size_t)(yc1 * W_ + xc0) * 32);
            const h8* t11 = (const h8*)(vbp + (size_t)(yc1 * W_ + xc1) * 32);
            #pragma unroll
            for (int cc = 0; cc < 4; ++cc) {
                h8 cq = t10[cc], dq = t11[cc];
                const h2* cp = (const h2*)&cq;
                const h2* dp = (const h2*)&dq;
                const h2* rv2 = (const h2*)&r8[cc];
                #pragma unroll
                for (int jp = 0; jp < 4; ++jp) {
                    h2 fv = cp[jp] * w10h + dp[jp] * w11h;
                    int g = cc*2 + (jp >> 1);
                    sim[g] = fdot2f(fv, rv2[jp], sim[g]);
                }
            }
        }

        #pragma unroll
        for (int g = 0; g < G_; ++g) sim[g] *= 0.25f;

        // entropy of softmax(sim): ent = m + ln(es) - (sum e*sim)/es
        float m = sim[0];
        #pragma unroll
        for (int g = 1; g < G_; ++g) m = fmaxf(m, sim[g]);
        float es = 0.f, edot = 0.f;
        #pragma unroll
        for (int g = 0; g < G_; ++g) {
            float e = exp2f((sim[g] - m) * LOG2E_);
            es += e;
            edot = fmaf(e, sim[g], edot);
        }
        float inv_es = __builtin_amdgcn_rcpf(es);
        float ent = m + log2f(es) * LN2_ - edot * inv_es;

        // sigmoid(MLP(ent)) via table lerp
        float t = ent * (1023.0f / LN8_);
        t = fminf(fmaxf(t, 0.f), 1022.999f);
        int it = (int)t;
        float fr = t - (float)it;
        float lo = tab_s[it], hi = tab_s[it + 1];
        float sig = fmaf(hi - lo, fr, lo);

        // max over 32 depth lanes per pixel — shuffle only
        float mv = sig;
        #pragma unroll
        for (int k = 16; k >= 1; k >>= 1)
            mv = fmaxf(mv, __shfl_xor(mv, k, 64));
        if (d == 0)
            out_vw[(b * 4 + (v - 1)) * HW_ + p] = mv;

        #pragma unroll
        for (int g = 0; g < G_; ++g) simsum[g] = fmaf(sim[g], mv, simsum[g]);
        wsum += mv;
    }

    float wn = __builtin_amdgcn_rcpf(wsum + 1e-6f);
    #pragma unroll
    for (int g = 0; g < G_; ++g) s_sim[g][d][pxl] = simsum[g] * wn;
    __syncthreads();

    const int tx = tid & 31;
    const int ty = tid >> 5;
    float* so = out_sim + (size_t)b * G_ * DHW_ + ty * HW_ + h * W_ + w0 + tx;
    h8 hv;
    #pragma unroll
    for (int g = 0; g < G_; ++g) {
        float val = s_sim[g][ty][tx];
        so[(size_t)g * DHW_] = val;
        hv[g] = (_Float16)val;
    }
    *(h8*)(simh + ((size_t)(b * D_ + ty) * HW_ + h * W_ + w0 + tx) * 8) = hv;
}

// ---------------- conv3d via MFMA implicit GEMM, 4 d-slices per block ----------------
// K = 28 taps x 8 ic, M = 16 (oc pad), N = 16 voxels.
// A[m=lane&15][k=quad*8+j] from wh (global, L2 broadcast); B from LDS halo.
// grid (W/32, H/8, B*D/4), block 256.

__global__ __launch_bounds__(256) void k_conv1m(
    const _Float16* __restrict__ in,   // [B][D][H][W][8]
    const _Float16* __restrict__ wh,   // [28][16][8]
    const float* __restrict__ bias,    // [8]
    _Float16* __restrict__ outh)       // [B][D][H][W][8]
{
    __shared__ _Float16 halo[6*10*34*8];   // 32640 B
    const int tid = threadIdx.x;
    const int w0 = blockIdx.x * 32;
    const int h0 = blockIdx.y * 8;
    const int z  = blockIdx.z;
    const int b  = z >> 3;
    const int d0 = (z & 7) * 4;

    for (int pos = tid; pos < 2040; pos += 256) {
        int wx = pos % 34; int r = pos / 34; int hy = r % 10; int dz = r / 10;
        int gw = w0 + wx - 1, gh = h0 + hy - 1, gd = d0 + dz - 1;
        uint4 val = make_uint4(0u, 0u, 0u, 0u);
        if (gw >= 0 && gw < W_ && gh >= 0 && gh < H_ && gd >= 0 && gd < D_)
            val = *(const uint4*)(in + (((size_t)(b*D_ + gd)*H_ + gh)*W_ + gw)*8);
        *(uint4*)(halo + pos*8) = val;
    }

    const int wave = tid >> 6, lane = tid & 63;
    const int n = lane & 15, quad = lane >> 4;

    h8 afrag[7];
    int chunkoff[7];
    #pragma unroll
    for (int c = 0; c < 7; ++c) {
        int tap = c*4 + quad;
        afrag[c] = *(const h8*)(wh + (tap*16 + n)*8);
        int tapc = tap > 26 ? 26 : tap;
        int dz = tapc / 9; int rem = tapc - dz*9;
        int hyo = rem / 3; int wxo = rem - hyo*3;
        chunkoff[c] = ((dz*10 + hyo)*34 + wxo)*8;
    }
    f4 binit;
    #pragma unroll
    for (int reg = 0; reg < 4; ++reg)
        binit[reg] = (quad < 2) ? bias[quad*4 + reg] : 0.f;

    __syncthreads();

    #pragma unroll
    for (int it = 0; it < 4; ++it) {
        int t = wave*4 + it;
        int h_row = t >> 1, whalf = t & 1;
        int tileoff = (h_row*34 + whalf*16 + n)*8;
        #pragma unroll
        for (int dout = 0; dout < 4; ++dout) {
            f4 acc = binit;
            #pragma unroll
            for (int c = 0; c < 7; ++c) {
                h8 bfrag = *(const h8*)(halo + chunkoff[c] + dout*2720 + tileoff);
                acc = __builtin_amdgcn_mfma_f32_16x16x32_f16(afrag[c], bfrag, acc, 0, 0, 0);
            }
            if (quad < 2) {
                h4 hv;
                #pragma unroll
                for (int reg = 0; reg < 4; ++reg) hv[reg] = (_Float16)fmaxf(acc[reg], 0.f);
                *(h4*)(outh + (((size_t)(b*D_ + d0 + dout)*H_ + h0 + h_row)*W_ + w0 + whalf*16 + n)*8 + quad*4) = hv;
            }
        }
    }
}

__global__ __launch_bounds__(256) void k_conv2m(
    const _Float16* __restrict__ in,   // [B][D][H][W][8]
    const _Float16* __restrict__ wh,   // [28][16][8] (m==0 live)
    const float* __restrict__ bias,    // [1]
    float* __restrict__ out)           // [B][D][H][W]
{
    __shared__ _Float16 halo[6*10*34*8];
    const int tid = threadIdx.x;
    const int w0 = blockIdx.x * 32;
    const int h0 = blockIdx.y * 8;
    const int z  = blockIdx.z;
    const int b  = z >> 3;
    const int d0 = (z & 7) * 4;

    for (int pos = tid; pos < 2040; pos += 256) {
        int wx = pos % 34; int r = pos / 34; int hy = r % 10; int dz = r / 10;
        int gw = w0 + wx - 1, gh = h0 + hy - 1, gd = d0 + dz - 1;
        uint4 val = make_uint4(0u, 0u, 0u, 0u);
        if (gw >= 0 && gw < W_ && gh >= 0 && gh < H_ && gd >= 0 && gd < D_)
            val = *(const uint4*)(in + (((size_t)(b*D_ + gd)*H_ + gh)*W_ + gw)*8);
        *(uint4*)(halo + pos*8) = val;
    }

    const int wave = tid >> 6, lane = tid & 63;
    const int n = lane & 15, quad = lane >> 4;

    h8 afrag[7];
    int chunkoff[7];
    #pragma unroll
    for (int c = 0; c < 7; ++c) {
        int tap = c*4 + quad;
        afrag[c] = *(const h8*)(wh + (tap*16 + n)*8);
        int tapc = tap > 26 ? 26 : tap;
        int dz = tapc / 9; int rem = tapc - dz*9;
        int hyo = rem / 3; int wxo = rem - hyo*3;
        chunkoff[c] = ((dz*10 + hyo)*34 + wxo)*8;
    }
    const float b0 = bias[0];

    __syncthreads();

    #pragma unroll
    for (int it = 0; it < 4; ++it) {
        int t = wave*4 + it;
        int h_row = t >> 1, whalf = t & 1;
        int tileoff = (h_row*34 + whalf*16 + n)*8;
        #pragma unroll
        for (int dout = 0; dout < 4; ++dout) {
            f4 acc;
            acc[0] = (quad == 0) ? b0 : 0.f;
            acc[1] = 0.f; acc[2] = 0.f; acc[3] = 0.f;
            #pragma unroll
            for (int c = 0; c < 7; ++c) {
                h8 bfrag = *(const h8*)(halo + chunkoff[c] + dout*2720 + tileoff);
                acc = __builtin_amdgcn_mfma_f32_16x16x32_f16(afrag[c], bfrag, acc, 0, 0, 0);
            }
            if (quad == 0)
                out[(((size_t)(b*D_ + d0 + dout)*H_ + h0 + h_row)*W_ + w0 + whalf*16 + n)] = acc[0];
        }
    }
}

// ---------------- final: softmax over D, depth, confidence ----------------
__global__ __launch_bounds__(256) void k_final(
    const float* __restrict__ pvp,
    const float* __restrict__ depthv,
    float* __restrict__ out_depth,
    float* __restrict__ out_conf)
{
    int i = blockIdx.x * 256 + threadIdx.x;
    if (i >= B_ * HW_) return;
    int b = i / HW_;
    int p = i - b * HW_;

    const float* pp = pvp + b * DHW_ + p;
    const float* dv = depthv + b * DHW_ + p;

    float x[D_];
    float m = -3.4e38f;
    #pragma unroll
    for (int d = 0; d < D_; ++d) { x[d] = pp[d * HW_]; m = fmaxf(m, x[d]); }
    float s = 0.f;
    #pragma unroll
    for (int d = 0; d < D_; ++d) { x[d] = exp2f((x[d] - m) * LOG2E_); s += x[d]; }
    float inv = 1.f / s;

    float dep = 0.f, fd = 0.f;
    #pragma unroll
    for (int d = 0; d < D_; ++d) {
        float pv = x[d] * inv;
        x[d] = pv;
        dep = fmaf(pv, dv[d * HW_], dep);
        fd  = fmaf(pv, (float)d, fd);
    }
    int di = (int)fd;
    di = di < 0 ? 0 : (di > D_ - 1 ? D_ - 1 : di);
    float conf = 0.f;
    #pragma unroll
    for (int k = 0; k < 4; ++k) {
        int idx = di - 1 + k;
        if (idx >= 0 && idx < D_) conf += x[idx];
    }
    out_depth[i] = dep;
    out_conf[i]  = conf;
}

// ---------------- launch ----------------
extern "C" void kernel_launch(void* const* d_in, const int* in_sizes, int n_in,
                              void* d_out, int out_size, void* d_ws, size_t ws_size,
                              hipStream_t stream) {
    const float* feat   = (const float*)d_in[0];
    const float* pm     = (const float*)d_in[1];
    const float* depthv = (const float*)d_in[2];
    const float* reg_w1 = (const float*)d_in[3];
    const float* reg_b1 = (const float*)d_in[4];
    const float* reg_w2 = (const float*)d_in[5];
    const float* reg_b2 = (const float*)d_in[6];
    const float* pw_w1  = (const float*)d_in[7];
    const float* pw_b1  = (const float*)d_in[8];
    const float* pw_w2  = (const float*)d_in[9];
    const float* pw_b2  = (const float*)d_in[10];
    const float* pw_w3  = (const float*)d_in[11];
    const float* pw_b3  = (const float*)d_in[12];

    float* out = (float*)d_out;
    float* out_depth = out;
    float* out_conf  = out + B_*HW_;
    float* out_vw    = out + 2*B_*HW_;
    float* out_pvp   = out_vw + B_*4*HW_;
    float* out_sim   = out_pvp + B_*DHW_;

    float* ws      = (float*)d_ws;
    float* proj_ws = ws;                        // 96 floats
    float* tabw    = ws + 128;                  // 1024 floats
    _Float16* wh1  = (_Float16*)(ws + 1152);    // 3584 halves
    _Float16* wh2  = (_Float16*)(ws + 2944);    // 3584 halves
    _Float16* featT = (_Float16*)(ws + 4736);   // 6.55M halves, dead after k_main
    _Float16* hidh  = (_Float16*)(ws + 4736);   // 10.49M halves, overwrites featT
    _Float16* simh  = (_Float16*)(ws + 4736 + 5242880); // 10.49M halves

    hipLaunchKernelGGL(k_proj, dim3(1), dim3(1024), 0, stream,
                       pm, pw_w1, pw_b1, pw_w2, pw_b2, pw_w3, pw_b3,
                       reg_w1, reg_w2, proj_ws, tabw, wh1, wh2);

    hipLaunchKernelGGL(k_transpose, dim3(HW_/32, V_*B_), dim3(32, 32), 0, stream,
                       feat, featT);

    hipLaunchKernelGGL(k_main, dim3(W_/32, H_, B_), dim3(1024), 0, stream,
                       featT, depthv, proj_ws, tabw, out_vw, out_sim, simh);

    hipLaunchKernelGGL(k_conv1m, dim3(W_/32, H_/8, B_*D_/4), dim3(256), 0, stream,
                       simh, wh1, reg_b1, hidh);

    hipLaunchKernelGGL(k_conv2m, dim3(W_/32, H_/8, B_*D_/4), dim3(256), 0, stream,
                       hidh, wh2, reg_b2, out_pvp);

    hipLaunchKernelGGL(k_final, dim3((B_*HW_ + 255)/256), dim3(256), 0, stream,
                       out_pvp, depthv, out_depth, out_conf);
}